// Round 4
// baseline (307.741 us; speedup 1.0000x reference)
//
#include <hip/hip_runtime.h>
#include <hip/hip_bf16.h>

typedef __hip_bfloat16 bf16;
typedef unsigned short ushort;
typedef unsigned char uchar;
typedef long i64;   // 64-bit on amdgcn
typedef __attribute__((ext_vector_type(4))) float f32x4;

#define B_ 8
#define T_ 1024
#define D_ 1024
#define N_ 256
#define L_ 768
#define H_ 16
#define HD_ 64
#define TE_ 2048

__device__ __forceinline__ void gld16(const void* g, void* l) {
    __builtin_amdgcn_global_load_lds((const __attribute__((address_space(1))) void*)g,
                                     (__attribute__((address_space(3))) void*)l,
                                     16, 0, 0);
}

__device__ __forceinline__ float bitf(unsigned u) { return __uint_as_float(u); }

// pack 4 f32 -> 4 fp8 e4m3 bytes (OCP on gfx950)
__device__ __forceinline__ int pk4_fp8(float a, float b, float c, float d) {
    int p = __builtin_amdgcn_cvt_pk_fp8_f32(a, b, 0, false);
    p = __builtin_amdgcn_cvt_pk_fp8_f32(c, d, p, true);
    return p;
}
__device__ __forceinline__ uchar pk1_fp8(float a) {
    int p = __builtin_amdgcn_cvt_pk_fp8_f32(a, a, 0, false);
    return (uchar)(p & 0xff);
}
// manual e4m3fn decode (avoids unverified cvt builtin)
__device__ __forceinline__ float dec8(uchar b) {
    int e = (b >> 3) & 15, m = b & 7;
    float mag = e ? (float)(8 + m) * bitf((unsigned)(117 + e) << 23)   // (1+m/8)*2^(e-7)
                  : (float)m * bitf(118u << 23);                        // m * 2^-9
    return (b & 0x80) ? -mag : mag;
}

// wave-per-row LayerNorm -> fp8 (no barriers, coalesced 256B ld / 256B st)
template <int NV>
__device__ __forceinline__ void ln_row(const float* __restrict__ rp,
                                       const float* __restrict__ g,
                                       const float* __restrict__ bb,
                                       uchar* __restrict__ op, int lane) {
    float4 va[NV];
#pragma unroll
    for (int i = 0; i < NV; i++) va[i] = ((const float4*)rp)[i * 64 + lane];
    float s = 0.f, s2 = 0.f;
#pragma unroll
    for (int i = 0; i < NV; i++) {
        s  += va[i].x + va[i].y + va[i].z + va[i].w;
        s2 += va[i].x * va[i].x + va[i].y * va[i].y + va[i].z * va[i].z + va[i].w * va[i].w;
    }
#pragma unroll
    for (int off = 32; off; off >>= 1) {
        s  += __shfl_xor(s,  off, 64);
        s2 += __shfl_xor(s2, off, 64);
    }
    const float inv_n = 1.f / (float)(NV * 256);
    float mu = s * inv_n;
    float var = s2 * inv_n - mu * mu;
    float rstd = rsqrtf(var + 1e-5f);
#pragma unroll
    for (int i = 0; i < NV; i++) {
        float4 gv = ((const float4*)g)[i * 64 + lane];
        float4 bv = ((const float4*)bb)[i * 64 + lane];
        ((int*)op)[i * 64 + lane] = pk4_fp8((va[i].x - mu) * rstd * gv.x + bv.x,
                                            (va[i].y - mu) * rstd * gv.y + bv.y,
                                            (va[i].z - mu) * rstd * gv.z + bv.z,
                                            (va[i].w - mu) * rstd * gv.w + bv.w);
    }
}

// ===== prep: LN rows [0,2560) | tcvt [2560,3456) | emb1 [3456,3712) =======
__global__ __launch_bounds__(256) void prep_kernel(
        const float* __restrict__ x, const float* __restrict__ xf,
        const float* __restrict__ g1, const float* __restrict__ b1,
        const float* __restrict__ g2, const float* __restrict__ b2,
        const float* __restrict__ Wq, const float* __restrict__ Wk,
        const float* __restrict__ Wv, const float* __restrict__ Wo,
        const float* __restrict__ emb, const float* __restrict__ Wemb,
        uchar* __restrict__ xn8, uchar* __restrict__ xfn8,
        uchar* __restrict__ wq8, uchar* __restrict__ wk8,
        uchar* __restrict__ wv8, uchar* __restrict__ wo8,
        float* __restrict__ part) {
    __shared__ __align__(16) char smem[16384];
    int bid = blockIdx.x;
    int tid = threadIdx.x;
    if (bid < 2560) {
        int w = tid >> 6, lane = tid & 63;
        int row = bid * 4 + w;          // blocks 0..2047: x rows; 2048..2559: xf rows
        if (row < B_ * T_) {
            ln_row<4>(x + (size_t)row * D_, g1, b1, xn8 + (size_t)row * D_, lane);
        } else {
            int r = row - B_ * T_;
            ln_row<3>(xf + (size_t)r * L_, g2, b2, xfn8 + (size_t)r * L_, lane);
        }
    } else if (bid < 3456) {
        uchar (*t)[65] = (uchar(*)[65])smem;
        int id = bid - 2560;
        int xb = id & 15, y = id >> 4;
        const float* W; uchar* Wt; int K, ky;
        if (y < 16)      { W = Wq; Wt = wq8; K = 1024; ky = y; }
        else if (y < 28) { W = Wk; Wt = wk8; K = 768;  ky = y - 16; }
        else if (y < 40) { W = Wv; Wt = wv8; K = 768;  ky = y - 28; }
        else             { W = Wo; Wt = wo8; K = 1024; ky = y - 40; }
        int k0 = ky * 64, n0 = xb * 64;
#pragma unroll
        for (int i = 0; i < 16; i++) {
            int e = tid + i * 256;
            int r = e >> 6, c = e & 63;
            t[r][c] = pk1_fp8(W[(size_t)(k0 + r) * D_ + n0 + c]);
        }
        __syncthreads();
#pragma unroll
        for (int i = 0; i < 4; i++) {
            int e = tid + i * 256;
            int r = e >> 4, cg = (e & 15) * 4;
            unsigned u = (unsigned)t[cg][r] | ((unsigned)t[cg + 1][r] << 8)
                       | ((unsigned)t[cg + 2][r] << 16) | ((unsigned)t[cg + 3][r] << 24);
            *(unsigned*)&Wt[(size_t)(n0 + r) * K + k0 + cg] = u;
        }
    } else {
        float* se  = (float*)smem;
        float* red = (float*)(smem + 8192);
        int id = bid - 3456;
        int j0 = (id & 31) * 64;
        int ks = id >> 5;
        int tx = tid & 15, ty = tid >> 4;
        int w = tid >> 6, lane = tid & 63;
#pragma unroll
        for (int b = 0; b < 8; b++) {
            float xv = emb[b * TE_ + ks * 256 + tid];
            se[b * 256 + tid] = xv / (1.f + __expf(-xv));
        }
        __syncthreads();
        float acc[8][4] = {};
#pragma unroll 4
        for (int i = 0; i < 16; i++) {
            int e = ty + 16 * i;
            float4 wv = *(const float4*)&Wemb[(size_t)(ks * 256 + e) * 2048 + j0 + tx * 4];
#pragma unroll
            for (int b = 0; b < 8; b++) {
                float s = se[b * 256 + e];
                acc[b][0] += s * wv.x; acc[b][1] += s * wv.y;
                acc[b][2] += s * wv.z; acc[b][3] += s * wv.w;
            }
        }
#pragma unroll
        for (int b = 0; b < 8; b++)
#pragma unroll
            for (int m = 0; m < 4; m++) {
                float v = acc[b][m];
                v += __shfl_down(v, 32, 64);
                v += __shfl_down(v, 16, 64);
                if (lane < 16) red[(w * 8 + b) * 64 + lane * 4 + m] = v;
            }
        __syncthreads();
        for (int o = tid; o < 512; o += 256) {
            int b = o >> 6, jl = o & 63;
            float s = red[(0 * 8 + b) * 64 + jl] + red[(1 * 8 + b) * 64 + jl]
                    + red[(2 * 8 + b) * 64 + jl] + red[(3 * 8 + b) * 64 + jl];
            part[((size_t)ks * 8 + b) * 2048 + j0 + jl] = s;
        }
    }
}

// ===== fp8 MFMA GEMM body: 128x128 tile, BK=128, single-buffer DMA ========
// MODE 0: fp8 C (LDS-bounced coalesced store)  MODE 1: f32 C + res
// MODE 2: V-scatter pre-swizzled vT8
template <int MODE>
__device__ __forceinline__ void gemm_body(const uchar* __restrict__ Ap,
                                          const uchar* __restrict__ Bp,
                                          const float* __restrict__ bias,
                                          const float* __restrict__ res,
                                          void* __restrict__ Cout,
                                          int m0, int n0, int Ncols, int K,
                                          uchar* Ash, uchar* Bsh) {
    int tid = threadIdx.x;
    int w = tid >> 6, lane = tid & 63;
    int quad = lane >> 4, l15 = lane & 15;
    int wm = (w >> 1) * 64, wn = (w & 1) * 64;
    int lr8 = lane >> 3;
    int sc  = lane & 7;
    int gc  = sc ^ lr8;
    f32x4 acc[4][4] = {};
    for (int kt = 0; kt < K; kt += 128) {
#pragma unroll
        for (int j = 0; j < 4; j++) {
            int rbase = w * 32 + j * 8;
            gld16(&Ap[(size_t)(m0 + rbase + lr8) * K + kt + gc * 16], &Ash[rbase * 128]);
        }
#pragma unroll
        for (int j = 0; j < 4; j++) {
            int rbase = w * 32 + j * 8;
            gld16(&Bp[(size_t)(n0 + rbase + lr8) * K + kt + gc * 16], &Bsh[rbase * 128]);
        }
        __syncthreads();
#pragma unroll
        for (int kh = 0; kh < 4; kh++) {
            int c4 = kh * 2 + (quad >> 1);
            int sub = (quad & 1) * 8;
            int pos = (c4 ^ (l15 & 7)) * 16 + sub;
            i64 af[4], bfr[4];
#pragma unroll
            for (int mt = 0; mt < 4; mt++)
                af[mt] = *(const i64*)&Ash[(wm + mt * 16 + l15) * 128 + pos];
#pragma unroll
            for (int nt = 0; nt < 4; nt++)
                bfr[nt] = *(const i64*)&Bsh[(wn + nt * 16 + l15) * 128 + pos];
#pragma unroll
            for (int mt = 0; mt < 4; mt++)
#pragma unroll
                for (int nt = 0; nt < 4; nt++)
                    acc[mt][nt] = __builtin_amdgcn_mfma_f32_16x16x32_fp8_fp8(af[mt], bfr[nt], acc[mt][nt], 0, 0, 0);
        }
        __syncthreads();
    }
    if (MODE == 0) {
        // bounce fp8 tile through Ash (dead), then 16B coalesced stores
#pragma unroll
        for (int mt = 0; mt < 4; mt++)
#pragma unroll
            for (int nt = 0; nt < 4; nt++)
#pragma unroll
                for (int reg = 0; reg < 4; reg++) {
                    int rl = wm + mt * 16 + quad * 4 + reg;
                    int cl = wn + nt * 16 + l15;
                    Ash[rl * 128 + cl] = pk1_fp8(acc[mt][nt][reg] + bias[n0 + cl]);
                }
        __syncthreads();
#pragma unroll
        for (int i = 0; i < 4; i++) {
            int row = (tid >> 3) + i * 32;
            int ch = (tid & 7) * 16;
            *(int4*)&((uchar*)Cout)[(size_t)(m0 + row) * Ncols + n0 + ch] =
                *(const int4*)&Ash[row * 128 + ch];
        }
    } else {
#pragma unroll
        for (int mt = 0; mt < 4; mt++) {
#pragma unroll
            for (int nt = 0; nt < 4; nt++) {
#pragma unroll
                for (int reg = 0; reg < 4; reg++) {
                    int row = m0 + wm + mt * 16 + quad * 4 + reg;
                    int col = n0 + wn + nt * 16 + l15;
                    float v = acc[mt][nt][reg] + bias[col];
                    if (MODE == 1) {
                        v += res[(size_t)row * Ncols + col];
                        ((float*)Cout)[(size_t)row * Ncols + col] = v;
                    } else {
                        int b = row >> 8, n = row & 255;
                        int h = col >> 6, d = col & 63;
                        size_t addr = ((size_t)(b * 16 + h)) * 16384 + (size_t)d * 256
                                    + (((n >> 4) ^ (d & 15)) * 16) + (n & 15);
                        ((uchar*)Cout)[addr] = pk1_fp8(v);
                    }
                }
            }
        }
    }
}

// ===== fused Q/K/V projection + emb2 tail =================================
// DIAGNOSTIC ROUND: body repeated 3x (idempotent) so this kernel tops the
// rocprof dispatch table and exposes its true dur/MfmaUtil/FETCH/VGPR.
// __launch_bounds__(256,4): force <=128 VGPR -> 16 waves/CU.
__global__ __launch_bounds__(256, 4) void qkv_gemm(const uchar* __restrict__ xn8,
                                                   const uchar* __restrict__ xfn8,
                                                   const uchar* __restrict__ wq8,
                                                   const uchar* __restrict__ wk8,
                                                   const uchar* __restrict__ wv8,
                                                   const float* __restrict__ bq,
                                                   const float* __restrict__ bk,
                                                   const float* __restrict__ bv,
                                                   uchar* __restrict__ q8,
                                                   uchar* __restrict__ k8,
                                                   uchar* __restrict__ vT8,
                                                   const float* __restrict__ part,
                                                   const float* __restrict__ bemb,
                                                   float* __restrict__ embo) {
    __shared__ __align__(16) uchar Ash[128 * 128];
    __shared__ __align__(16) uchar Bsh[128 * 128];
    int bid = blockIdx.x;
#pragma unroll 1
    for (int rep = 0; rep < 3; rep++) {
        if (bid < 512) {
            gemm_body<0>(xn8, wq8, bq, nullptr, q8,
                         (bid & 63) * 128, (bid >> 6) * 128, D_, D_, Ash, Bsh);
        } else if (bid < 640) {
            int id = bid - 512;
            gemm_body<0>(xfn8, wk8, bk, nullptr, k8,
                         (id & 15) * 128, (id >> 4) * 128, D_, L_, Ash, Bsh);
        } else if (bid < 768) {
            int id = bid - 640;
            gemm_body<2>(xfn8, wv8, bv, nullptr, vT8,
                         (id & 15) * 128, (id >> 4) * 128, D_, L_, Ash, Bsh);
        } else {
            int o = (bid - 768) * 256 + threadIdx.x;
            int b = o >> 11, j = o & 2047;
            float s = bemb[j];
#pragma unroll
            for (int ks = 0; ks < 8; ks++) s += part[((size_t)ks * 8 + b) * 2048 + j];
            embo[o] = s;
        }
        __syncthreads();   // rep N's LDS reads done before rep N+1 restages
    }
}

// ===== output projection + residual (f32 out) =============================
__global__ __launch_bounds__(256, 4) void out_gemm(const uchar* __restrict__ a8,
                                                   const uchar* __restrict__ wo8,
                                                   const float* __restrict__ bout,
                                                   const float* __restrict__ x,
                                                   float* __restrict__ out) {
    __shared__ __align__(16) uchar Ash[128 * 128];
    __shared__ __align__(16) uchar Bsh[128 * 128];
    int bid = blockIdx.x;
    gemm_body<1>(a8, wo8, bout, x, out,
                 (bid & 63) * 128, (bid >> 6) * 128, D_, D_, Ash, Bsh);
}

// ===== full-fp8 MFMA attention: block = 64 q-rows x one (b,h) =============
// 1D grid, XCD-bijective map: all 16 t-blocks of a (b,h) land on one XCD
// so K/V tiles are fetched from HBM once, not 8x. LDS 32 KB -> 5 blocks/CU.
__global__ __launch_bounds__(256) void attn_mfma(const uchar* __restrict__ q8,
                                                 const uchar* __restrict__ k8,
                                                 const uchar* __restrict__ vT8,
                                                 uchar* __restrict__ y8) {
    __shared__ __align__(16) uchar KV[16384];  // K image, then V image
    __shared__ __align__(16) uchar P[16384];   // padded Q (first 8 KB), then P rows
    int tid = threadIdx.x;
    int w = tid >> 6, lane = tid & 63;
    int quad = lane >> 4, l15 = lane & 15;
    int bid = blockIdx.x;
    int work = (bid & 7) * 256 + (bid >> 3);   // bijective: 2048 = 8 * 256
    int t0 = (work & 15) * 64;
    int bh = work >> 4;
    int b = bh >> 4, h = bh & 15;
    int lln = lane >> 3, sp = lane & 7;

    // K DMA: 4 gld16/wave; line dn holds rows 2dn,2dn+1; slot p <- chunk c8=p^(dn&7)
#pragma unroll
    for (int j = 0; j < 4; j++) {
        int dn = w * 32 + j * 8 + lln;
        int c8 = sp ^ (dn & 7);
        int n = dn * 2 + (c8 >> 2);
        gld16(&k8[(size_t)(b * N_ + n) * D_ + h * 64 + (c8 & 3) * 16],
              &KV[(w * 32 + j * 8) * 128]);
    }
    // Q DMA into P region: 2 gld16/wave; row r padded to 128B, slot p <- chunk (p^(r&7))&3
#pragma unroll
    for (int j = 0; j < 2; j++) {
        int r = w * 16 + j * 8 + lln;
        int c = (sp ^ (r & 7)) & 3;
        gld16(&q8[(size_t)(b * T_ + t0 + r) * D_ + h * 64 + c * 16],
              &P[(w * 16 + j * 8) * 128]);
    }
    __syncthreads();

    // S = Q K^T (fp8 mfma, K-dim 64 = 2 steps)
    int qrow = w * 16 + l15;
    i64 aq[2];
#pragma unroll
    for (int kk2 = 0; kk2 < 2; kk2++) {
        int chunk = kk2 * 2 + (quad >> 1);
        aq[kk2] = *(const i64*)&P[qrow * 128 + ((chunk ^ (qrow & 7)) * 16) + (quad & 1) * 8];
    }
    f32x4 sf[16];
#pragma unroll
    for (int nt = 0; nt < 16; nt++) {
        int n = nt * 16 + l15;
        int dn = n >> 1, hn = n & 1;
        int c80 = (hn * 4 + 0 + (quad >> 1)) ^ (dn & 7);
        int c81 = (hn * 4 + 2 + (quad >> 1)) ^ (dn & 7);
        i64 b0 = *(const i64*)&KV[dn * 128 + c80 * 16 + (quad & 1) * 8];
        i64 b1 = *(const i64*)&KV[dn * 128 + c81 * 16 + (quad & 1) * 8];
        f32x4 z = {};
        f32x4 t = __builtin_amdgcn_mfma_f32_16x16x32_fp8_fp8(aq[0], b0, z, 0, 0, 0);
        sf[nt] = __builtin_amdgcn_mfma_f32_16x16x32_fp8_fp8(aq[1], b1, t, 0, 0, 0);
    }
    __syncthreads();   // K reads done -> KV reusable for V

    // V DMA (identity copy of pre-swizzled vT8) — latency hidden under softmax
    const uchar* vbase = vT8 + (size_t)(b * 16 + h) * 16384;
#pragma unroll
    for (int j = 0; j < 4; j++) {
        gld16(&vbase[(w * 4 + j) * 1024 + lane * 16], &KV[(w * 4 + j) * 1024]);
    }

    // softmax over N (rows = quad*4+reg), no max-subtraction
    const float scale = 0.125f;
    float sm[4] = {0.f, 0.f, 0.f, 0.f};
#pragma unroll
    for (int nt = 0; nt < 16; nt++)
#pragma unroll
        for (int reg = 0; reg < 4; reg++) {
            float e = __expf(sf[nt][reg] * scale);
            sf[nt][reg] = e;
            sm[reg] += e;
        }
#pragma unroll
    for (int off = 1; off < 16; off <<= 1)
#pragma unroll
        for (int reg = 0; reg < 4; reg++)
            sm[reg] += __shfl_xor(sm[reg], off, 64);
    float inv[4];
#pragma unroll
    for (int reg = 0; reg < 4; reg++) inv[reg] = 1.f / sm[reg];

    // P writes (fp8 bytes, A-operand-ready layout) — overwrites Q (dead)
#pragma unroll
    for (int nt = 0; nt < 16; nt++)
#pragma unroll
        for (int reg = 0; reg < 4; reg++) {
            int r = w * 16 + quad * 4 + reg;
            int n = nt * 16 + l15;
            P[r * 256 + (((n >> 4) ^ (r & 15)) * 16) + (n & 15)] = pk1_fp8(sf[nt][reg]);
        }
    __syncthreads();   // drains V DMA + P writes visible

    // O = P @ V (fp8 mfma, K-dim 256 = 8 steps)
    f32x4 of[4] = {};
    int prow = w * 16 + l15;
#pragma unroll
    for (int kk = 0; kk < 8; kk++) {
        int ck = kk * 2 + (quad >> 1);
        i64 ap = *(const i64*)&P[prow * 256 + ((ck ^ (prow & 15)) * 16) + (quad & 1) * 8];
#pragma unroll
        for (int dt = 0; dt < 4; dt++) {
            int d = dt * 16 + l15;
            i64 bv = *(const i64*)&KV[d * 256 + ((ck ^ (d & 15)) * 16) + (quad & 1) * 8];
            of[dt] = __builtin_amdgcn_mfma_f32_16x16x32_fp8_fp8(ap, bv, of[dt], 0, 0, 0);
        }
    }
    // bounce O through P (dead) for coalesced 16B stores
    __syncthreads();   // all P/KV reads done
#pragma unroll
    for (int dt = 0; dt < 4; dt++)
#pragma unroll
        for (int reg = 0; reg < 4; reg++) {
            int rl = w * 16 + quad * 4 + reg;
            P[rl * 64 + dt * 16 + l15] = pk1_fp8(of[dt][reg] * inv[reg]);
        }
    __syncthreads();
    {
        int row = tid >> 2, ch = (tid & 3) * 16;
        *(int4*)&y8[(size_t)(b * T_ + t0 + row) * D_ + h * 64 + ch] =
            *(const int4*)&P[row * 64 + ch];
    }
}

// ===== stylization: wave-per-row, fp8 y in -> fp8 a out (no barriers) =====
__global__ __launch_bounds__(256) void styl_kernel(const uchar* __restrict__ y8,
                                                   const float* __restrict__ g,
                                                   const float* __restrict__ bb,
                                                   const float* __restrict__ embo,
                                                   uchar* __restrict__ a8) {
    int tid = threadIdx.x, w = tid >> 6, lane = tid & 63;
    int row = blockIdx.x * 4 + w;
    int b = row >> 10;
    const uchar* rp = y8 + (size_t)row * D_;
    uchar* op = a8 + (size_t)row * D_;
    float v[16];
    float s = 0.f, s2 = 0.f;
#pragma unroll
    for (int i = 0; i < 4; i++) {
        unsigned u = ((const unsigned*)rp)[i * 64 + lane];
#pragma unroll
        for (int j = 0; j < 4; j++) {
            float f = dec8((uchar)(u >> (8 * j)));
            v[i * 4 + j] = f; s += f; s2 += f * f;
        }
    }
#pragma unroll
    for (int off = 32; off; off >>= 1) {
        s  += __shfl_xor(s,  off, 64);
        s2 += __shfl_xor(s2, off, 64);
    }
    float mu = s * (1.f / 1024.f);
    float rstd = rsqrtf(s2 * (1.f / 1024.f) - mu * mu + 1e-5f);
#pragma unroll
    for (int i = 0; i < 4; i++) {
        int c4 = i * 64 + lane;
        float4 gv  = ((const float4*)g)[c4];
        float4 bv  = ((const float4*)bb)[c4];
        float4 scv = ((const float4*)(embo + b * 2048))[c4];
        float4 shv = ((const float4*)(embo + b * 2048 + 1024))[c4];
        float h0 = (v[i*4+0] - mu) * rstd * gv.x + bv.x;
        float h1 = (v[i*4+1] - mu) * rstd * gv.y + bv.y;
        float h2 = (v[i*4+2] - mu) * rstd * gv.z + bv.z;
        float h3 = (v[i*4+3] - mu) * rstd * gv.w + bv.w;
        h0 = h0 * (1.f + scv.x) + shv.x;
        h1 = h1 * (1.f + scv.y) + shv.y;
        h2 = h2 * (1.f + scv.z) + shv.z;
        h3 = h3 * (1.f + scv.w) + shv.w;
        h0 = h0 / (1.f + __expf(-h0));
        h1 = h1 / (1.f + __expf(-h1));
        h2 = h2 / (1.f + __expf(-h2));
        h3 = h3 / (1.f + __expf(-h3));
        ((int*)op)[c4] = pk4_fp8(h0, h1, h2, h3);
    }
}

extern "C" void kernel_launch(void* const* d_in, const int* in_sizes, int n_in,
                              void* d_out, int out_size, void* d_ws, size_t ws_size,
                              hipStream_t stream) {
    const float* x    = (const float*)d_in[0];
    const float* xf   = (const float*)d_in[1];
    const float* emb  = (const float*)d_in[2];
    const float* ln_g = (const float*)d_in[3];
    const float* ln_b = (const float*)d_in[4];
    const float* cln_g= (const float*)d_in[5];
    const float* cln_b= (const float*)d_in[6];
    const float* Wq   = (const float*)d_in[7];
    const float* bq   = (const float*)d_in[8];
    const float* Wk   = (const float*)d_in[9];
    const float* bk   = (const float*)d_in[10];
    const float* Wv   = (const float*)d_in[11];
    const float* bv   = (const float*)d_in[12];
    const float* sln_g= (const float*)d_in[13];
    const float* sln_b= (const float*)d_in[14];
    const float* Wemb = (const float*)d_in[15];
    const float* bemb = (const float*)d_in[16];
    const float* Wout = (const float*)d_in[17];
    const float* bout = (const float*)d_in[18];
    float* out = (float*)d_out;

    char* wsp = (char*)d_ws;
    const size_t MB = 1024 * 1024;
    uchar* xn8  = (uchar*)(wsp);                  // 8192x1024 fp8   8 MB
    uchar* xfn8 = (uchar*)(wsp + 8 * MB);         // 2048x768  fp8  1.5 MB
    uchar* wq8  = (uchar*)(wsp + 10 * MB);        // 1024x1024 fp8   1 MB
    uchar* wk8  = (uchar*)(wsp + 11 * MB);        //                .75 MB
    uchar* wv8  = (uchar*)(wsp + 12 * MB);        //                .75 MB
    uchar* wo8  = (uchar*)(wsp + 13 * MB);        //                 1 MB
    uchar* q8   = (uchar*)(wsp + 14 * MB);        // 8192x1024 fp8   8 MB
    uchar* k8   = (uchar*)(wsp + 22 * MB);        // 2048x1024 fp8   2 MB
    uchar* vT8  = (uchar*)(wsp + 24 * MB);        // pre-swizzled    2 MB
    uchar* y8   = (uchar*)(wsp + 26 * MB);        // 8192x1024 fp8   8 MB
    uchar* a8   = (uchar*)(wsp + 34 * MB);        // 8192x1024 fp8   8 MB
    float* embo = (float*)(wsp + 42 * MB);        // 8x2048    f32  64 KB
    float* part = (float*)(wsp + 43 * MB);        // 8x8x2048  f32  512 KB

    prep_kernel<<<3712, 256, 0, stream>>>(x, xf, ln_g, ln_b, cln_g, cln_b,
                                          Wq, Wk, Wv, Wout, emb, Wemb,
                                          xn8, xfn8, wq8, wk8, wv8, wo8, part);

    qkv_gemm<<<832, 256, 0, stream>>>(xn8, xfn8, wq8, wk8, wv8, bq, bk, bv,
                                      q8, k8, vT8, part, bemb, embo);

    attn_mfma<<<2048, 256, 0, stream>>>(q8, k8, vT8, y8);

    styl_kernel<<<2048, 256, 0, stream>>>(y8, sln_g, sln_b, embo, a8);

    out_gemm<<<512, 256, 0, stream>>>(a8, wo8, bout, x, out);
}

// Round 5
// 274.226 us; speedup vs baseline: 1.1222x; 1.1222x over previous
//
#include <hip/hip_runtime.h>
#include <hip/hip_bf16.h>

typedef __hip_bfloat16 bf16;
typedef unsigned short ushort;
typedef unsigned char uchar;
typedef long i64;   // 64-bit on amdgcn
typedef __attribute__((ext_vector_type(4))) float f32x4;

#define B_ 8
#define T_ 1024
#define D_ 1024
#define N_ 256
#define L_ 768
#define H_ 16
#define HD_ 64
#define TE_ 2048

__device__ __forceinline__ void gld16(const void* g, void* l) {
    __builtin_amdgcn_global_load_lds((const __attribute__((address_space(1))) void*)g,
                                     (__attribute__((address_space(3))) void*)l,
                                     16, 0, 0);
}

__device__ __forceinline__ float bitf(unsigned u) { return __uint_as_float(u); }

// pack 4 f32 -> 4 fp8 e4m3 bytes (OCP on gfx950)
__device__ __forceinline__ int pk4_fp8(float a, float b, float c, float d) {
    int p = __builtin_amdgcn_cvt_pk_fp8_f32(a, b, 0, false);
    p = __builtin_amdgcn_cvt_pk_fp8_f32(c, d, p, true);
    return p;
}
__device__ __forceinline__ uchar pk1_fp8(float a) {
    int p = __builtin_amdgcn_cvt_pk_fp8_f32(a, a, 0, false);
    return (uchar)(p & 0xff);
}
// manual e4m3fn decode (avoids unverified cvt builtin)
__device__ __forceinline__ float dec8(uchar b) {
    int e = (b >> 3) & 15, m = b & 7;
    float mag = e ? (float)(8 + m) * bitf((unsigned)(117 + e) << 23)   // (1+m/8)*2^(e-7)
                  : (float)m * bitf(118u << 23);                        // m * 2^-9
    return (b & 0x80) ? -mag : mag;
}

// wave-per-row LayerNorm -> fp8 (no barriers, coalesced 256B ld / 256B st)
template <int NV>
__device__ __forceinline__ void ln_row(const float* __restrict__ rp,
                                       const float* __restrict__ g,
                                       const float* __restrict__ bb,
                                       uchar* __restrict__ op, int lane) {
    float4 va[NV];
#pragma unroll
    for (int i = 0; i < NV; i++) va[i] = ((const float4*)rp)[i * 64 + lane];
    float s = 0.f, s2 = 0.f;
#pragma unroll
    for (int i = 0; i < NV; i++) {
        s  += va[i].x + va[i].y + va[i].z + va[i].w;
        s2 += va[i].x * va[i].x + va[i].y * va[i].y + va[i].z * va[i].z + va[i].w * va[i].w;
    }
#pragma unroll
    for (int off = 32; off; off >>= 1) {
        s  += __shfl_xor(s,  off, 64);
        s2 += __shfl_xor(s2, off, 64);
    }
    const float inv_n = 1.f / (float)(NV * 256);
    float mu = s * inv_n;
    float var = s2 * inv_n - mu * mu;
    float rstd = rsqrtf(var + 1e-5f);
#pragma unroll
    for (int i = 0; i < NV; i++) {
        float4 gv = ((const float4*)g)[i * 64 + lane];
        float4 bv = ((const float4*)bb)[i * 64 + lane];
        ((int*)op)[i * 64 + lane] = pk4_fp8((va[i].x - mu) * rstd * gv.x + bv.x,
                                            (va[i].y - mu) * rstd * gv.y + bv.y,
                                            (va[i].z - mu) * rstd * gv.z + bv.z,
                                            (va[i].w - mu) * rstd * gv.w + bv.w);
    }
}

// ===== prep: LN rows [0,2560) | tcvt [2560,3456) | emb1 [3456,3712) =======
__global__ __launch_bounds__(256) void prep_kernel(
        const float* __restrict__ x, const float* __restrict__ xf,
        const float* __restrict__ g1, const float* __restrict__ b1,
        const float* __restrict__ g2, const float* __restrict__ b2,
        const float* __restrict__ Wq, const float* __restrict__ Wk,
        const float* __restrict__ Wv, const float* __restrict__ Wo,
        const float* __restrict__ emb, const float* __restrict__ Wemb,
        uchar* __restrict__ xn8, uchar* __restrict__ xfn8,
        uchar* __restrict__ wq8, uchar* __restrict__ wk8,
        uchar* __restrict__ wv8, uchar* __restrict__ wo8,
        float* __restrict__ part) {
    __shared__ __align__(16) char smem[16384];
    int bid = blockIdx.x;
    int tid = threadIdx.x;
    if (bid < 2560) {
        int w = tid >> 6, lane = tid & 63;
        int row = bid * 4 + w;          // blocks 0..2047: x rows; 2048..2559: xf rows
        if (row < B_ * T_) {
            ln_row<4>(x + (size_t)row * D_, g1, b1, xn8 + (size_t)row * D_, lane);
        } else {
            int r = row - B_ * T_;
            ln_row<3>(xf + (size_t)r * L_, g2, b2, xfn8 + (size_t)r * L_, lane);
        }
    } else if (bid < 3456) {
        uchar (*t)[65] = (uchar(*)[65])smem;
        int id = bid - 2560;
        int xb = id & 15, y = id >> 4;
        const float* W; uchar* Wt; int K, ky;
        if (y < 16)      { W = Wq; Wt = wq8; K = 1024; ky = y; }
        else if (y < 28) { W = Wk; Wt = wk8; K = 768;  ky = y - 16; }
        else if (y < 40) { W = Wv; Wt = wv8; K = 768;  ky = y - 28; }
        else             { W = Wo; Wt = wo8; K = 1024; ky = y - 40; }
        int k0 = ky * 64, n0 = xb * 64;
#pragma unroll
        for (int i = 0; i < 16; i++) {
            int e = tid + i * 256;
            int r = e >> 6, c = e & 63;
            t[r][c] = pk1_fp8(W[(size_t)(k0 + r) * D_ + n0 + c]);
        }
        __syncthreads();
#pragma unroll
        for (int i = 0; i < 4; i++) {
            int e = tid + i * 256;
            int r = e >> 4, cg = (e & 15) * 4;
            unsigned u = (unsigned)t[cg][r] | ((unsigned)t[cg + 1][r] << 8)
                       | ((unsigned)t[cg + 2][r] << 16) | ((unsigned)t[cg + 3][r] << 24);
            *(unsigned*)&Wt[(size_t)(n0 + r) * K + k0 + cg] = u;
        }
    } else {
        float* se  = (float*)smem;
        float* red = (float*)(smem + 8192);
        int id = bid - 3456;
        int j0 = (id & 31) * 64;
        int ks = id >> 5;
        int tx = tid & 15, ty = tid >> 4;
        int w = tid >> 6, lane = tid & 63;
#pragma unroll
        for (int b = 0; b < 8; b++) {
            float xv = emb[b * TE_ + ks * 256 + tid];
            se[b * 256 + tid] = xv / (1.f + __expf(-xv));
        }
        __syncthreads();
        float acc[8][4] = {};
#pragma unroll 4
        for (int i = 0; i < 16; i++) {
            int e = ty + 16 * i;
            float4 wv = *(const float4*)&Wemb[(size_t)(ks * 256 + e) * 2048 + j0 + tx * 4];
#pragma unroll
            for (int b = 0; b < 8; b++) {
                float s = se[b * 256 + e];
                acc[b][0] += s * wv.x; acc[b][1] += s * wv.y;
                acc[b][2] += s * wv.z; acc[b][3] += s * wv.w;
            }
        }
#pragma unroll
        for (int b = 0; b < 8; b++)
#pragma unroll
            for (int m = 0; m < 4; m++) {
                float v = acc[b][m];
                v += __shfl_down(v, 32, 64);
                v += __shfl_down(v, 16, 64);
                if (lane < 16) red[(w * 8 + b) * 64 + lane * 4 + m] = v;
            }
        __syncthreads();
        for (int o = tid; o < 512; o += 256) {
            int b = o >> 6, jl = o & 63;
            float s = red[(0 * 8 + b) * 64 + jl] + red[(1 * 8 + b) * 64 + jl]
                    + red[(2 * 8 + b) * 64 + jl] + red[(3 * 8 + b) * 64 + jl];
            part[((size_t)ks * 8 + b) * 2048 + j0 + jl] = s;
        }
    }
}

// ===== fp8 MFMA GEMM body: 128x128 tile, BK=64 (m145 mirror) ==============
// 16 KB LDS -> 8 blocks/CU (32 waves, HW cap). 4-slot XOR swizzle per row.
// MODE 0: fp8 C (LDS-bounced coalesced store; bounce = full 16 KB SH)
// MODE 1: f32 C + res   MODE 2: V-scatter pre-swizzled vT8
template <int MODE>
__device__ __forceinline__ void gemm_body(const uchar* __restrict__ Ap,
                                          const uchar* __restrict__ Bp,
                                          const float* __restrict__ bias,
                                          const float* __restrict__ res,
                                          void* __restrict__ Cout,
                                          int m0, int n0, int Ncols, int K,
                                          uchar* Ash, uchar* Bsh) {
    int tid = threadIdx.x;
    int w = tid >> 6, lane = tid & 63;
    int quad = lane >> 4, l15 = lane & 15;
    int wm = (w >> 1) * 64, wn = (w & 1) * 64;
    int lr4 = lane >> 2;          // row-within-16 for staging
    int sp4 = lane & 3;           // slot 0..3
    f32x4 acc[4][4] = {};
    for (int kt = 0; kt < K; kt += 64) {
#pragma unroll
        for (int j = 0; j < 2; j++) {
            int r = w * 32 + j * 16 + lr4;
            int gc = sp4 ^ (r & 3);
            gld16(&Ap[(size_t)(m0 + r) * K + kt + gc * 16], &Ash[(w * 32 + j * 16) * 64]);
        }
#pragma unroll
        for (int j = 0; j < 2; j++) {
            int r = w * 32 + j * 16 + lr4;
            int gc = sp4 ^ (r & 3);
            gld16(&Bp[(size_t)(n0 + r) * K + kt + gc * 16], &Bsh[(w * 32 + j * 16) * 64]);
        }
        __syncthreads();
#pragma unroll
        for (int kh = 0; kh < 2; kh++) {
            int c4 = kh * 2 + (quad >> 1);
            int sub = (quad & 1) * 8;
            int pos = (c4 ^ (l15 & 3)) * 16 + sub;
            i64 af[4], bfr[4];
#pragma unroll
            for (int mt = 0; mt < 4; mt++)
                af[mt] = *(const i64*)&Ash[(wm + mt * 16 + l15) * 64 + pos];
#pragma unroll
            for (int nt = 0; nt < 4; nt++)
                bfr[nt] = *(const i64*)&Bsh[(wn + nt * 16 + l15) * 64 + pos];
#pragma unroll
            for (int mt = 0; mt < 4; mt++)
#pragma unroll
                for (int nt = 0; nt < 4; nt++)
                    acc[mt][nt] = __builtin_amdgcn_mfma_f32_16x16x32_fp8_fp8(af[mt], bfr[nt], acc[mt][nt], 0, 0, 0);
        }
        __syncthreads();
    }
    if (MODE == 0) {
        // bounce fp8 tile through Ash..Bsh (16 KB contiguous, dead), 16B stores
#pragma unroll
        for (int mt = 0; mt < 4; mt++)
#pragma unroll
            for (int nt = 0; nt < 4; nt++)
#pragma unroll
                for (int reg = 0; reg < 4; reg++) {
                    int rl = wm + mt * 16 + quad * 4 + reg;
                    int cl = wn + nt * 16 + l15;
                    Ash[rl * 128 + cl] = pk1_fp8(acc[mt][nt][reg] + bias[n0 + cl]);
                }
        __syncthreads();
#pragma unroll
        for (int i = 0; i < 4; i++) {
            int row = (tid >> 3) + i * 32;
            int ch = (tid & 7) * 16;
            *(int4*)&((uchar*)Cout)[(size_t)(m0 + row) * Ncols + n0 + ch] =
                *(const int4*)&Ash[row * 128 + ch];
        }
    } else {
#pragma unroll
        for (int mt = 0; mt < 4; mt++) {
#pragma unroll
            for (int nt = 0; nt < 4; nt++) {
#pragma unroll
                for (int reg = 0; reg < 4; reg++) {
                    int row = m0 + wm + mt * 16 + quad * 4 + reg;
                    int col = n0 + wn + nt * 16 + l15;
                    float v = acc[mt][nt][reg] + bias[col];
                    if (MODE == 1) {
                        v += res[(size_t)row * Ncols + col];
                        ((float*)Cout)[(size_t)row * Ncols + col] = v;
                    } else {
                        int b = row >> 8, n = row & 255;
                        int h = col >> 6, d = col & 63;
                        size_t addr = ((size_t)(b * 16 + h)) * 16384 + (size_t)d * 256
                                    + (((n >> 4) ^ (d & 15)) * 16) + (n & 15);
                        ((uchar*)Cout)[addr] = pk1_fp8(v);
                    }
                }
            }
        }
    }
}

// ===== fused Q/K/V projection + emb2 tail =================================
__global__ __launch_bounds__(256, 4) void qkv_gemm(const uchar* __restrict__ xn8,
                                                   const uchar* __restrict__ xfn8,
                                                   const uchar* __restrict__ wq8,
                                                   const uchar* __restrict__ wk8,
                                                   const uchar* __restrict__ wv8,
                                                   const float* __restrict__ bq,
                                                   const float* __restrict__ bk,
                                                   const float* __restrict__ bv,
                                                   uchar* __restrict__ q8,
                                                   uchar* __restrict__ k8,
                                                   uchar* __restrict__ vT8,
                                                   const float* __restrict__ part,
                                                   const float* __restrict__ bemb,
                                                   float* __restrict__ embo) {
    __shared__ __align__(16) uchar SH[16384];   // A 8K | B 8K (bounce uses all 16K)
    int bid = blockIdx.x;
    if (bid < 512) {
        gemm_body<0>(xn8, wq8, bq, nullptr, q8,
                     (bid & 63) * 128, (bid >> 6) * 128, D_, D_, SH, SH + 8192);
    } else if (bid < 640) {
        int id = bid - 512;
        gemm_body<0>(xfn8, wk8, bk, nullptr, k8,
                     (id & 15) * 128, (id >> 4) * 128, D_, L_, SH, SH + 8192);
    } else if (bid < 768) {
        int id = bid - 640;
        gemm_body<2>(xfn8, wv8, bv, nullptr, vT8,
                     (id & 15) * 128, (id >> 4) * 128, D_, L_, SH, SH + 8192);
    } else {
        int o = (bid - 768) * 256 + threadIdx.x;
        int b = o >> 11, j = o & 2047;
        float s = bemb[j];
#pragma unroll
        for (int ks = 0; ks < 8; ks++) s += part[((size_t)ks * 8 + b) * 2048 + j];
        embo[o] = s;
    }
}

// ===== output projection + residual (f32 out) =============================
__global__ __launch_bounds__(256, 4) void out_gemm(const uchar* __restrict__ a8,
                                                   const uchar* __restrict__ wo8,
                                                   const float* __restrict__ bout,
                                                   const float* __restrict__ x,
                                                   float* __restrict__ out) {
    __shared__ __align__(16) uchar SH[16384];
    int bid = blockIdx.x;
    gemm_body<1>(a8, wo8, bout, x, out,
                 (bid & 63) * 128, (bid >> 6) * 128, D_, D_, SH, SH + 8192);
}

// ===== full-fp8 MFMA attention: block = 64 q-rows x one (b,h) =============
// DIAGNOSTIC ROUND: body repeated 3x (idempotent) to expose true
// dur/MfmaUtil/conflicts in the rocprof top-5 next round.
__global__ __launch_bounds__(256) void attn_mfma(const uchar* __restrict__ q8,
                                                 const uchar* __restrict__ k8,
                                                 const uchar* __restrict__ vT8,
                                                 uchar* __restrict__ y8) {
    __shared__ __align__(16) uchar KV[16384];  // K image, then V image
    __shared__ __align__(16) uchar P[16384];   // padded Q (first 8 KB), then P rows
    int tid = threadIdx.x;
    int w = tid >> 6, lane = tid & 63;
    int quad = lane >> 4, l15 = lane & 15;
    int bid = blockIdx.x;
    int work = (bid & 7) * 256 + (bid >> 3);   // bijective: 2048 = 8 * 256
    int t0 = (work & 15) * 64;
    int bh = work >> 4;
    int b = bh >> 4, h = bh & 15;
    int lln = lane >> 3, sp = lane & 7;

#pragma unroll 1
    for (int rep = 0; rep < 3; rep++) {
        // K DMA: 4 gld16/wave; line dn holds rows 2dn,2dn+1; slot p <- chunk c8=p^(dn&7)
#pragma unroll
        for (int j = 0; j < 4; j++) {
            int dn = w * 32 + j * 8 + lln;
            int c8 = sp ^ (dn & 7);
            int n = dn * 2 + (c8 >> 2);
            gld16(&k8[(size_t)(b * N_ + n) * D_ + h * 64 + (c8 & 3) * 16],
                  &KV[(w * 32 + j * 8) * 128]);
        }
        // Q DMA into P region: row r padded to 128B, slot p <- chunk (p^(r&7))&3
#pragma unroll
        for (int j = 0; j < 2; j++) {
            int r = w * 16 + j * 8 + lln;
            int c = (sp ^ (r & 7)) & 3;
            gld16(&q8[(size_t)(b * T_ + t0 + r) * D_ + h * 64 + c * 16],
                  &P[(w * 16 + j * 8) * 128]);
        }
        __syncthreads();

        // S = Q K^T (fp8 mfma, K-dim 64 = 2 steps)
        int qrow = w * 16 + l15;
        i64 aq[2];
#pragma unroll
        for (int kk2 = 0; kk2 < 2; kk2++) {
            int chunk = kk2 * 2 + (quad >> 1);
            aq[kk2] = *(const i64*)&P[qrow * 128 + ((chunk ^ (qrow & 7)) * 16) + (quad & 1) * 8];
        }
        f32x4 sf[16];
#pragma unroll
        for (int nt = 0; nt < 16; nt++) {
            int n = nt * 16 + l15;
            int dn = n >> 1, hn = n & 1;
            int c80 = (hn * 4 + 0 + (quad >> 1)) ^ (dn & 7);
            int c81 = (hn * 4 + 2 + (quad >> 1)) ^ (dn & 7);
            i64 b0 = *(const i64*)&KV[dn * 128 + c80 * 16 + (quad & 1) * 8];
            i64 b1 = *(const i64*)&KV[dn * 128 + c81 * 16 + (quad & 1) * 8];
            f32x4 z = {};
            f32x4 t = __builtin_amdgcn_mfma_f32_16x16x32_fp8_fp8(aq[0], b0, z, 0, 0, 0);
            sf[nt] = __builtin_amdgcn_mfma_f32_16x16x32_fp8_fp8(aq[1], b1, t, 0, 0, 0);
        }
        __syncthreads();   // K reads done -> KV reusable for V

        // V DMA (identity copy of pre-swizzled vT8) — latency hidden under softmax
        const uchar* vbase = vT8 + (size_t)(b * 16 + h) * 16384;
#pragma unroll
        for (int j = 0; j < 4; j++) {
            gld16(&vbase[(w * 4 + j) * 1024 + lane * 16], &KV[(w * 4 + j) * 1024]);
        }

        // softmax over N (rows = quad*4+reg), no max-subtraction
        const float scale = 0.125f;
        float sm[4] = {0.f, 0.f, 0.f, 0.f};
#pragma unroll
        for (int nt = 0; nt < 16; nt++)
#pragma unroll
            for (int reg = 0; reg < 4; reg++) {
                float e = __expf(sf[nt][reg] * scale);
                sf[nt][reg] = e;
                sm[reg] += e;
            }
#pragma unroll
        for (int off = 1; off < 16; off <<= 1)
#pragma unroll
            for (int reg = 0; reg < 4; reg++)
                sm[reg] += __shfl_xor(sm[reg], off, 64);
        float inv[4];
#pragma unroll
        for (int reg = 0; reg < 4; reg++) inv[reg] = 1.f / sm[reg];

        // P writes (fp8 bytes, A-operand-ready layout) — overwrites Q (dead)
#pragma unroll
        for (int nt = 0; nt < 16; nt++)
#pragma unroll
            for (int reg = 0; reg < 4; reg++) {
                int r = w * 16 + quad * 4 + reg;
                int n = nt * 16 + l15;
                P[r * 256 + (((n >> 4) ^ (r & 15)) * 16) + (n & 15)] = pk1_fp8(sf[nt][reg]);
            }
        __syncthreads();   // drains V DMA + P writes visible

        // O = P @ V (fp8 mfma, K-dim 256 = 8 steps)
        f32x4 of[4] = {};
        int prow = w * 16 + l15;
#pragma unroll
        for (int kk = 0; kk < 8; kk++) {
            int ck = kk * 2 + (quad >> 1);
            i64 ap = *(const i64*)&P[prow * 256 + ((ck ^ (prow & 15)) * 16) + (quad & 1) * 8];
#pragma unroll
            for (int dt = 0; dt < 4; dt++) {
                int d = dt * 16 + l15;
                i64 bv = *(const i64*)&KV[d * 256 + ((ck ^ (d & 15)) * 16) + (quad & 1) * 8];
                of[dt] = __builtin_amdgcn_mfma_f32_16x16x32_fp8_fp8(ap, bv, of[dt], 0, 0, 0);
            }
        }
        // bounce O through P (dead) for coalesced 16B stores
        __syncthreads();   // all P/KV reads done
#pragma unroll
        for (int dt = 0; dt < 4; dt++)
#pragma unroll
            for (int reg = 0; reg < 4; reg++) {
                int rl = w * 16 + quad * 4 + reg;
                P[rl * 64 + dt * 16 + l15] = pk1_fp8(of[dt][reg] * inv[reg]);
            }
        __syncthreads();
        {
            int row = tid >> 2, ch = (tid & 3) * 16;
            *(int4*)&y8[(size_t)(b * T_ + t0 + row) * D_ + h * 64 + ch] =
                *(const int4*)&P[row * 64 + ch];
        }
        __syncthreads();   // P reads done before next rep overwrites
    }
}

// ===== stylization: wave-per-row, fp8 y in -> fp8 a out (no barriers) =====
__global__ __launch_bounds__(256) void styl_kernel(const uchar* __restrict__ y8,
                                                   const float* __restrict__ g,
                                                   const float* __restrict__ bb,
                                                   const float* __restrict__ embo,
                                                   uchar* __restrict__ a8) {
    int tid = threadIdx.x, w = tid >> 6, lane = tid & 63;
    int row = blockIdx.x * 4 + w;
    int b = row >> 10;
    const uchar* rp = y8 + (size_t)row * D_;
    uchar* op = a8 + (size_t)row * D_;
    float v[16];
    float s = 0.f, s2 = 0.f;
#pragma unroll
    for (int i = 0; i < 4; i++) {
        unsigned u = ((const unsigned*)rp)[i * 64 + lane];
#pragma unroll
        for (int j = 0; j < 4; j++) {
            float f = dec8((uchar)(u >> (8 * j)));
            v[i * 4 + j] = f; s += f; s2 += f * f;
        }
    }
#pragma unroll
    for (int off = 32; off; off >>= 1) {
        s  += __shfl_xor(s,  off, 64);
        s2 += __shfl_xor(s2, off, 64);
    }
    float mu = s * (1.f / 1024.f);
    float rstd = rsqrtf(s2 * (1.f / 1024.f) - mu * mu + 1e-5f);
#pragma unroll
    for (int i = 0; i < 4; i++) {
        int c4 = i * 64 + lane;
        float4 gv  = ((const float4*)g)[c4];
        float4 bv  = ((const float4*)bb)[c4];
        float4 scv = ((const float4*)(embo + b * 2048))[c4];
        float4 shv = ((const float4*)(embo + b * 2048 + 1024))[c4];
        float h0 = (v[i*4+0] - mu) * rstd * gv.x + bv.x;
        float h1 = (v[i*4+1] - mu) * rstd * gv.y + bv.y;
        float h2 = (v[i*4+2] - mu) * rstd * gv.z + bv.z;
        float h3 = (v[i*4+3] - mu) * rstd * gv.w + bv.w;
        h0 = h0 * (1.f + scv.x) + shv.x;
        h1 = h1 * (1.f + scv.y) + shv.y;
        h2 = h2 * (1.f + scv.z) + shv.z;
        h3 = h3 * (1.f + scv.w) + shv.w;
        h0 = h0 / (1.f + __expf(-h0));
        h1 = h1 / (1.f + __expf(-h1));
        h2 = h2 / (1.f + __expf(-h2));
        h3 = h3 / (1.f + __expf(-h3));
        ((int*)op)[c4] = pk4_fp8(h0, h1, h2, h3);
    }
}

extern "C" void kernel_launch(void* const* d_in, const int* in_sizes, int n_in,
                              void* d_out, int out_size, void* d_ws, size_t ws_size,
                              hipStream_t stream) {
    const float* x    = (const float*)d_in[0];
    const float* xf   = (const float*)d_in[1];
    const float* emb  = (const float*)d_in[2];
    const float* ln_g = (const float*)d_in[3];
    const float* ln_b = (const float*)d_in[4];
    const float* cln_g= (const float*)d_in[5];
    const float* cln_b= (const float*)d_in[6];
    const float* Wq   = (const float*)d_in[7];
    const float* bq   = (const float*)d_in[8];
    const float* Wk   = (const float*)d_in[9];
    const float* bk   = (const float*)d_in[10];
    const float* Wv   = (const float*)d_in[11];
    const float* bv   = (const float*)d_in[12];
    const float* sln_g= (const float*)d_in[13];
    const float* sln_b= (const float*)d_in[14];
    const float* Wemb = (const float*)d_in[15];
    const float* bemb = (const float*)d_in[16];
    const float* Wout = (const float*)d_in[17];
    const float* bout = (const float*)d_in[18];
    float* out = (float*)d_out;

    char* wsp = (char*)d_ws;
    const size_t MB = 1024 * 1024;
    uchar* xn8  = (uchar*)(wsp);                  // 8192x1024 fp8   8 MB
    uchar* xfn8 = (uchar*)(wsp + 8 * MB);         // 2048x768  fp8  1.5 MB
    uchar* wq8  = (uchar*)(wsp + 10 * MB);        // 1024x1024 fp8   1 MB
    uchar* wk8  = (uchar*)(wsp + 11 * MB);        //                .75 MB
    uchar* wv8  = (uchar*)(wsp + 12 * MB);        //                .75 MB
    uchar* wo8  = (uchar*)(wsp + 13 * MB);        //                 1 MB
    uchar* q8   = (uchar*)(wsp + 14 * MB);        // 8192x1024 fp8   8 MB
    uchar* k8   = (uchar*)(wsp + 22 * MB);        // 2048x1024 fp8   2 MB
    uchar* vT8  = (uchar*)(wsp + 24 * MB);        // pre-swizzled    2 MB
    uchar* y8   = (uchar*)(wsp + 26 * MB);        // 8192x1024 fp8   8 MB
    uchar* a8   = (uchar*)(wsp + 34 * MB);        // 8192x1024 fp8   8 MB
    float* embo = (float*)(wsp + 42 * MB);        // 8x2048    f32  64 KB
    float* part = (float*)(wsp + 43 * MB);        // 8x8x2048  f32  512 KB

    prep_kernel<<<3712, 256, 0, stream>>>(x, xf, ln_g, ln_b, cln_g, cln_b,
                                          Wq, Wk, Wv, Wout, emb, Wemb,
                                          xn8, xfn8, wq8, wk8, wv8, wo8, part);

    qkv_gemm<<<832, 256, 0, stream>>>(xn8, xfn8, wq8, wk8, wv8, bq, bk, bv,
                                      q8, k8, vT8, part, bemb, embo);

    attn_mfma<<<2048, 256, 0, stream>>>(q8, k8, vT8, y8);

    styl_kernel<<<2048, 256, 0, stream>>>(y8, sln_g, sln_b, embo, a8);

    out_gemm<<<512, 256, 0, stream>>>(a8, wo8, bout, x, out);
}

// Round 6
// 233.815 us; speedup vs baseline: 1.3162x; 1.1728x over previous
//
#include <hip/hip_runtime.h>
#include <hip/hip_bf16.h>

typedef __hip_bfloat16 bf16;
typedef unsigned short ushort;
typedef unsigned char uchar;
typedef long i64;   // 64-bit on amdgcn
typedef __attribute__((ext_vector_type(4))) float f32x4;

#define B_ 8
#define T_ 1024
#define D_ 1024
#define N_ 256
#define L_ 768
#define H_ 16
#define HD_ 64
#define TE_ 2048

__device__ __forceinline__ void gld16(const void* g, void* l) {
    __builtin_amdgcn_global_load_lds((const __attribute__((address_space(1))) void*)g,
                                     (__attribute__((address_space(3))) void*)l,
                                     16, 0, 0);
}

__device__ __forceinline__ float bitf(unsigned u) { return __uint_as_float(u); }

// pack 4 f32 -> 4 fp8 e4m3 bytes (OCP on gfx950)
__device__ __forceinline__ int pk4_fp8(float a, float b, float c, float d) {
    int p = __builtin_amdgcn_cvt_pk_fp8_f32(a, b, 0, false);
    p = __builtin_amdgcn_cvt_pk_fp8_f32(c, d, p, true);
    return p;
}
__device__ __forceinline__ uchar pk1_fp8(float a) {
    int p = __builtin_amdgcn_cvt_pk_fp8_f32(a, a, 0, false);
    return (uchar)(p & 0xff);
}
// manual e4m3fn decode (avoids unverified cvt builtin)
__device__ __forceinline__ float dec8(uchar b) {
    int e = (b >> 3) & 15, m = b & 7;
    float mag = e ? (float)(8 + m) * bitf((unsigned)(117 + e) << 23)   // (1+m/8)*2^(e-7)
                  : (float)m * bitf(118u << 23);                        // m * 2^-9
    return (b & 0x80) ? -mag : mag;
}

// wave-per-row LayerNorm -> fp8 (no barriers, coalesced 256B ld / 256B st)
template <int NV>
__device__ __forceinline__ void ln_row(const float* __restrict__ rp,
                                       const float* __restrict__ g,
                                       const float* __restrict__ bb,
                                       uchar* __restrict__ op, int lane) {
    float4 va[NV];
#pragma unroll
    for (int i = 0; i < NV; i++) va[i] = ((const float4*)rp)[i * 64 + lane];
    float s = 0.f, s2 = 0.f;
#pragma unroll
    for (int i = 0; i < NV; i++) {
        s  += va[i].x + va[i].y + va[i].z + va[i].w;
        s2 += va[i].x * va[i].x + va[i].y * va[i].y + va[i].z * va[i].z + va[i].w * va[i].w;
    }
#pragma unroll
    for (int off = 32; off; off >>= 1) {
        s  += __shfl_xor(s,  off, 64);
        s2 += __shfl_xor(s2, off, 64);
    }
    const float inv_n = 1.f / (float)(NV * 256);
    float mu = s * inv_n;
    float var = s2 * inv_n - mu * mu;
    float rstd = rsqrtf(var + 1e-5f);
#pragma unroll
    for (int i = 0; i < NV; i++) {
        float4 gv = ((const float4*)g)[i * 64 + lane];
        float4 bv = ((const float4*)bb)[i * 64 + lane];
        ((int*)op)[i * 64 + lane] = pk4_fp8((va[i].x - mu) * rstd * gv.x + bv.x,
                                            (va[i].y - mu) * rstd * gv.y + bv.y,
                                            (va[i].z - mu) * rstd * gv.z + bv.z,
                                            (va[i].w - mu) * rstd * gv.w + bv.w);
    }
}

// ===== prep: LN rows [0,2560) | tcvt [2560,3456) | emb1 [3456,3712) =======
__global__ __launch_bounds__(256) void prep_kernel(
        const float* __restrict__ x, const float* __restrict__ xf,
        const float* __restrict__ g1, const float* __restrict__ b1,
        const float* __restrict__ g2, const float* __restrict__ b2,
        const float* __restrict__ Wq, const float* __restrict__ Wk,
        const float* __restrict__ Wv, const float* __restrict__ Wo,
        const float* __restrict__ emb, const float* __restrict__ Wemb,
        uchar* __restrict__ xn8, uchar* __restrict__ xfn8,
        uchar* __restrict__ wq8, uchar* __restrict__ wk8,
        uchar* __restrict__ wv8, uchar* __restrict__ wo8,
        float* __restrict__ part) {
    __shared__ __align__(16) char smem[16384];
    int bid = blockIdx.x;
    int tid = threadIdx.x;
    if (bid < 2560) {
        int w = tid >> 6, lane = tid & 63;
        int row = bid * 4 + w;          // blocks 0..2047: x rows; 2048..2559: xf rows
        if (row < B_ * T_) {
            ln_row<4>(x + (size_t)row * D_, g1, b1, xn8 + (size_t)row * D_, lane);
        } else {
            int r = row - B_ * T_;
            ln_row<3>(xf + (size_t)r * L_, g2, b2, xfn8 + (size_t)r * L_, lane);
        }
    } else if (bid < 3456) {
        uchar (*t)[65] = (uchar(*)[65])smem;
        int id = bid - 2560;
        int xb = id & 15, y = id >> 4;
        const float* W; uchar* Wt; int K, ky;
        if (y < 16)      { W = Wq; Wt = wq8; K = 1024; ky = y; }
        else if (y < 28) { W = Wk; Wt = wk8; K = 768;  ky = y - 16; }
        else if (y < 40) { W = Wv; Wt = wv8; K = 768;  ky = y - 28; }
        else             { W = Wo; Wt = wo8; K = 1024; ky = y - 40; }
        int k0 = ky * 64, n0 = xb * 64;
#pragma unroll
        for (int i = 0; i < 16; i++) {
            int e = tid + i * 256;
            int r = e >> 6, c = e & 63;
            t[r][c] = pk1_fp8(W[(size_t)(k0 + r) * D_ + n0 + c]);
        }
        __syncthreads();
#pragma unroll
        for (int i = 0; i < 4; i++) {
            int e = tid + i * 256;
            int r = e >> 4, cg = (e & 15) * 4;
            unsigned u = (unsigned)t[cg][r] | ((unsigned)t[cg + 1][r] << 8)
                       | ((unsigned)t[cg + 2][r] << 16) | ((unsigned)t[cg + 3][r] << 24);
            *(unsigned*)&Wt[(size_t)(n0 + r) * K + k0 + cg] = u;
        }
    } else {
        float* se  = (float*)smem;
        float* red = (float*)(smem + 8192);
        int id = bid - 3456;
        int j0 = (id & 31) * 64;
        int ks = id >> 5;
        int tx = tid & 15, ty = tid >> 4;
        int w = tid >> 6, lane = tid & 63;
#pragma unroll
        for (int b = 0; b < 8; b++) {
            float xv = emb[b * TE_ + ks * 256 + tid];
            se[b * 256 + tid] = xv / (1.f + __expf(-xv));
        }
        __syncthreads();
        float acc[8][4] = {};
#pragma unroll 4
        for (int i = 0; i < 16; i++) {
            int e = ty + 16 * i;
            float4 wv = *(const float4*)&Wemb[(size_t)(ks * 256 + e) * 2048 + j0 + tx * 4];
#pragma unroll
            for (int b = 0; b < 8; b++) {
                float s = se[b * 256 + e];
                acc[b][0] += s * wv.x; acc[b][1] += s * wv.y;
                acc[b][2] += s * wv.z; acc[b][3] += s * wv.w;
            }
        }
#pragma unroll
        for (int b = 0; b < 8; b++)
#pragma unroll
            for (int m = 0; m < 4; m++) {
                float v = acc[b][m];
                v += __shfl_down(v, 32, 64);
                v += __shfl_down(v, 16, 64);
                if (lane < 16) red[(w * 8 + b) * 64 + lane * 4 + m] = v;
            }
        __syncthreads();
        for (int o = tid; o < 512; o += 256) {
            int b = o >> 6, jl = o & 63;
            float s = red[(0 * 8 + b) * 64 + jl] + red[(1 * 8 + b) * 64 + jl]
                    + red[(2 * 8 + b) * 64 + jl] + red[(3 * 8 + b) * 64 + jl];
            part[((size_t)ks * 8 + b) * 2048 + j0 + jl] = s;
        }
    }
}

// ===== fp8 MFMA GEMM body: 128x128 tile, BK=64, 2-PHASE double-buffer =====
// T3 minimum recipe: stage(t+1) issued BEFORE compute(t); ONE barrier/step
// (the __syncthreads drain covers vmcnt). 4x8KB LDS buffers, static indexing.
// MODE 0: fp8 C (LDS-bounced coalesced store)  MODE 1: f32 C + res
// MODE 2: V-scatter pre-swizzled vT8
template <int MODE>
__device__ __forceinline__ void gemm_body(const uchar* __restrict__ Ap,
                                          const uchar* __restrict__ Bp,
                                          const float* __restrict__ bias,
                                          const float* __restrict__ res,
                                          void* __restrict__ Cout,
                                          int m0, int n0, int Ncols, int K,
                                          uchar* SH) {
    int tid = threadIdx.x;
    int w = tid >> 6, lane = tid & 63;
    int quad = lane >> 4, l15 = lane & 15;
    int wm = (w >> 1) * 64, wn = (w & 1) * 64;
    int lr4 = lane >> 2;          // row-within-16 for staging
    int sp4 = lane & 3;           // slot 0..3
    uchar* A0 = SH;
    uchar* B0 = SH + 8192;
    uchar* A1 = SH + 16384;
    uchar* B1 = SH + 24576;
    f32x4 acc[4][4] = {};

    auto stage = [&](int kt, uchar* As, uchar* Bs) {
#pragma unroll
        for (int j = 0; j < 2; j++) {
            int r = w * 32 + j * 16 + lr4;
            int gc = sp4 ^ (r & 3);
            gld16(&Ap[(size_t)(m0 + r) * K + kt + gc * 16], &As[(w * 32 + j * 16) * 64]);
        }
#pragma unroll
        for (int j = 0; j < 2; j++) {
            int r = w * 32 + j * 16 + lr4;
            int gc = sp4 ^ (r & 3);
            gld16(&Bp[(size_t)(n0 + r) * K + kt + gc * 16], &Bs[(w * 32 + j * 16) * 64]);
        }
    };
    auto compute = [&](const uchar* As, const uchar* Bs) {
#pragma unroll
        for (int kh = 0; kh < 2; kh++) {
            int c4 = kh * 2 + (quad >> 1);
            int sub = (quad & 1) * 8;
            int pos = (c4 ^ (l15 & 3)) * 16 + sub;
            i64 af[4], bfr[4];
#pragma unroll
            for (int mt = 0; mt < 4; mt++)
                af[mt] = *(const i64*)&As[(wm + mt * 16 + l15) * 64 + pos];
#pragma unroll
            for (int nt = 0; nt < 4; nt++)
                bfr[nt] = *(const i64*)&Bs[(wn + nt * 16 + l15) * 64 + pos];
#pragma unroll
            for (int mt = 0; mt < 4; mt++)
#pragma unroll
                for (int nt = 0; nt < 4; nt++)
                    acc[mt][nt] = __builtin_amdgcn_mfma_f32_16x16x32_fp8_fp8(af[mt], bfr[nt], acc[mt][nt], 0, 0, 0);
        }
    };

    int nt2 = K >> 6;             // 16 (K=1024) or 12 (K=768) — always even
    stage(0, A0, B0);
    __syncthreads();
    for (int t = 0; t + 2 <= nt2; t += 2) {
        stage((t + 1) * 64, A1, B1);   // next tile in flight under compute
        compute(A0, B0);
        __syncthreads();               // drains vmcnt + syncs A0/B0 reads
        if (t + 2 < nt2) stage((t + 2) * 64, A0, B0);
        compute(A1, B1);
        __syncthreads();
    }

    if (MODE == 0) {
        // bounce fp8 tile through SH[0..16K) (dead), then 16B coalesced stores
#pragma unroll
        for (int mt = 0; mt < 4; mt++)
#pragma unroll
            for (int nt = 0; nt < 4; nt++)
#pragma unroll
                for (int reg = 0; reg < 4; reg++) {
                    int rl = wm + mt * 16 + quad * 4 + reg;
                    int cl = wn + nt * 16 + l15;
                    SH[rl * 128 + cl] = pk1_fp8(acc[mt][nt][reg] + bias[n0 + cl]);
                }
        __syncthreads();
#pragma unroll
        for (int i = 0; i < 4; i++) {
            int row = (tid >> 3) + i * 32;
            int ch = (tid & 7) * 16;
            *(int4*)&((uchar*)Cout)[(size_t)(m0 + row) * Ncols + n0 + ch] =
                *(const int4*)&SH[row * 128 + ch];
        }
    } else {
#pragma unroll
        for (int mt = 0; mt < 4; mt++) {
#pragma unroll
            for (int nt = 0; nt < 4; nt++) {
#pragma unroll
                for (int reg = 0; reg < 4; reg++) {
                    int row = m0 + wm + mt * 16 + quad * 4 + reg;
                    int col = n0 + wn + nt * 16 + l15;
                    float v = acc[mt][nt][reg] + bias[col];
                    if (MODE == 1) {
                        v += res[(size_t)row * Ncols + col];
                        ((float*)Cout)[(size_t)row * Ncols + col] = v;
                    } else {
                        int b = row >> 8, n = row & 255;
                        int h = col >> 6, d = col & 63;
                        size_t addr = ((size_t)(b * 16 + h)) * 16384 + (size_t)d * 256
                                    + (((n >> 4) ^ (d & 15)) * 16) + (n & 15);
                        ((uchar*)Cout)[addr] = pk1_fp8(v);
                    }
                }
            }
        }
    }
}

// ===== fused Q/K/V projection + emb2 tail =================================
__global__ __launch_bounds__(256, 4) void qkv_gemm(const uchar* __restrict__ xn8,
                                                   const uchar* __restrict__ xfn8,
                                                   const uchar* __restrict__ wq8,
                                                   const uchar* __restrict__ wk8,
                                                   const uchar* __restrict__ wv8,
                                                   const float* __restrict__ bq,
                                                   const float* __restrict__ bk,
                                                   const float* __restrict__ bv,
                                                   uchar* __restrict__ q8,
                                                   uchar* __restrict__ k8,
                                                   uchar* __restrict__ vT8,
                                                   const float* __restrict__ part,
                                                   const float* __restrict__ bemb,
                                                   float* __restrict__ embo) {
    __shared__ __align__(16) uchar SH[32768];   // A0|B0|A1|B1 (bounce uses first 16K)
    int bid = blockIdx.x;
    if (bid < 512) {
        gemm_body<0>(xn8, wq8, bq, nullptr, q8,
                     (bid & 63) * 128, (bid >> 6) * 128, D_, D_, SH);
    } else if (bid < 640) {
        int id = bid - 512;
        gemm_body<0>(xfn8, wk8, bk, nullptr, k8,
                     (id & 15) * 128, (id >> 4) * 128, D_, L_, SH);
    } else if (bid < 768) {
        int id = bid - 640;
        gemm_body<2>(xfn8, wv8, bv, nullptr, vT8,
                     (id & 15) * 128, (id >> 4) * 128, D_, L_, SH);
    } else {
        int o = (bid - 768) * 256 + threadIdx.x;
        int b = o >> 11, j = o & 2047;
        float s = bemb[j];
#pragma unroll
        for (int ks = 0; ks < 8; ks++) s += part[((size_t)ks * 8 + b) * 2048 + j];
        embo[o] = s;
    }
}

// ===== output projection + residual (f32 out) =============================
__global__ __launch_bounds__(256, 4) void out_gemm(const uchar* __restrict__ a8,
                                                   const uchar* __restrict__ wo8,
                                                   const float* __restrict__ bout,
                                                   const float* __restrict__ x,
                                                   float* __restrict__ out) {
    __shared__ __align__(16) uchar SH[32768];
    int bid = blockIdx.x;
    gemm_body<1>(a8, wo8, bout, x, out,
                 (bid & 63) * 128, (bid >> 6) * 128, D_, D_, SH);
}

// ===== full-fp8 MFMA attention: block = 64 q-rows x one (b,h) =============
// 1D grid, XCD-bijective map: all 16 t-blocks of a (b,h) land on one XCD
// so K/V tiles are fetched from HBM once. LDS 32 KB -> 5 blocks/CU.
__global__ __launch_bounds__(256) void attn_mfma(const uchar* __restrict__ q8,
                                                 const uchar* __restrict__ k8,
                                                 const uchar* __restrict__ vT8,
                                                 uchar* __restrict__ y8) {
    __shared__ __align__(16) uchar KV[16384];  // K image, then V image
    __shared__ __align__(16) uchar P[16384];   // padded Q (first 8 KB), then P rows
    int tid = threadIdx.x;
    int w = tid >> 6, lane = tid & 63;
    int quad = lane >> 4, l15 = lane & 15;
    int bid = blockIdx.x;
    int work = (bid & 7) * 256 + (bid >> 3);   // bijective: 2048 = 8 * 256
    int t0 = (work & 15) * 64;
    int bh = work >> 4;
    int b = bh >> 4, h = bh & 15;
    int lln = lane >> 3, sp = lane & 7;

    // K DMA: 4 gld16/wave; line dn holds rows 2dn,2dn+1; slot p <- chunk c8=p^(dn&7)
#pragma unroll
    for (int j = 0; j < 4; j++) {
        int dn = w * 32 + j * 8 + lln;
        int c8 = sp ^ (dn & 7);
        int n = dn * 2 + (c8 >> 2);
        gld16(&k8[(size_t)(b * N_ + n) * D_ + h * 64 + (c8 & 3) * 16],
              &KV[(w * 32 + j * 8) * 128]);
    }
    // Q DMA into P region: 2 gld16/wave; row r padded to 128B, slot p <- chunk (p^(r&7))&3
#pragma unroll
    for (int j = 0; j < 2; j++) {
        int r = w * 16 + j * 8 + lln;
        int c = (sp ^ (r & 7)) & 3;
        gld16(&q8[(size_t)(b * T_ + t0 + r) * D_ + h * 64 + c * 16],
              &P[(w * 16 + j * 8) * 128]);
    }
    __syncthreads();

    // S = Q K^T (fp8 mfma, K-dim 64 = 2 steps)
    int qrow = w * 16 + l15;
    i64 aq[2];
#pragma unroll
    for (int kk2 = 0; kk2 < 2; kk2++) {
        int chunk = kk2 * 2 + (quad >> 1);
        aq[kk2] = *(const i64*)&P[qrow * 128 + ((chunk ^ (qrow & 7)) * 16) + (quad & 1) * 8];
    }
    f32x4 sf[16];
#pragma unroll
    for (int nt = 0; nt < 16; nt++) {
        int n = nt * 16 + l15;
        int dn = n >> 1, hn = n & 1;
        int c80 = (hn * 4 + 0 + (quad >> 1)) ^ (dn & 7);
        int c81 = (hn * 4 + 2 + (quad >> 1)) ^ (dn & 7);
        i64 b0 = *(const i64*)&KV[dn * 128 + c80 * 16 + (quad & 1) * 8];
        i64 b1 = *(const i64*)&KV[dn * 128 + c81 * 16 + (quad & 1) * 8];
        f32x4 z = {};
        f32x4 t = __builtin_amdgcn_mfma_f32_16x16x32_fp8_fp8(aq[0], b0, z, 0, 0, 0);
        sf[nt] = __builtin_amdgcn_mfma_f32_16x16x32_fp8_fp8(aq[1], b1, t, 0, 0, 0);
    }
    __syncthreads();   // K reads done -> KV reusable for V

    // V DMA (identity copy of pre-swizzled vT8) — latency hidden under softmax
    const uchar* vbase = vT8 + (size_t)(b * 16 + h) * 16384;
#pragma unroll
    for (int j = 0; j < 4; j++) {
        gld16(&vbase[(w * 4 + j) * 1024 + lane * 16], &KV[(w * 4 + j) * 1024]);
    }

    // softmax over N (rows = quad*4+reg), no max-subtraction
    const float scale = 0.125f;
    float sm[4] = {0.f, 0.f, 0.f, 0.f};
#pragma unroll
    for (int nt = 0; nt < 16; nt++)
#pragma unroll
        for (int reg = 0; reg < 4; reg++) {
            float e = __expf(sf[nt][reg] * scale);
            sf[nt][reg] = e;
            sm[reg] += e;
        }
#pragma unroll
    for (int off = 1; off < 16; off <<= 1)
#pragma unroll
        for (int reg = 0; reg < 4; reg++)
            sm[reg] += __shfl_xor(sm[reg], off, 64);
    float inv[4];
#pragma unroll
    for (int reg = 0; reg < 4; reg++) inv[reg] = 1.f / sm[reg];

    // P writes (fp8 bytes, A-operand-ready layout) — overwrites Q (dead)
#pragma unroll
    for (int nt = 0; nt < 16; nt++)
#pragma unroll
        for (int reg = 0; reg < 4; reg++) {
            int r = w * 16 + quad * 4 + reg;
            int n = nt * 16 + l15;
            P[r * 256 + (((n >> 4) ^ (r & 15)) * 16) + (n & 15)] = pk1_fp8(sf[nt][reg]);
        }
    __syncthreads();   // drains V DMA + P writes visible

    // O = P @ V (fp8 mfma, K-dim 256 = 8 steps)
    f32x4 of[4] = {};
    int prow = w * 16 + l15;
#pragma unroll
    for (int kk = 0; kk < 8; kk++) {
        int ck = kk * 2 + (quad >> 1);
        i64 ap = *(const i64*)&P[prow * 256 + ((ck ^ (prow & 15)) * 16) + (quad & 1) * 8];
#pragma unroll
        for (int dt = 0; dt < 4; dt++) {
            int d = dt * 16 + l15;
            i64 bv = *(const i64*)&KV[d * 256 + ((ck ^ (d & 15)) * 16) + (quad & 1) * 8];
            of[dt] = __builtin_amdgcn_mfma_f32_16x16x32_fp8_fp8(ap, bv, of[dt], 0, 0, 0);
        }
    }
    // bounce O through P (dead) for coalesced 16B stores
    __syncthreads();   // all P/KV reads done
#pragma unroll
    for (int dt = 0; dt < 4; dt++)
#pragma unroll
        for (int reg = 0; reg < 4; reg++) {
            int rl = w * 16 + quad * 4 + reg;
            P[rl * 64 + dt * 16 + l15] = pk1_fp8(of[dt][reg] * inv[reg]);
        }
    __syncthreads();
    {
        int row = tid >> 2, ch = (tid & 3) * 16;
        *(int4*)&y8[(size_t)(b * T_ + t0 + row) * D_ + h * 64 + ch] =
            *(const int4*)&P[row * 64 + ch];
    }
}

// ===== stylization: wave-per-row, fp8 y in -> fp8 a out (no barriers) =====
__global__ __launch_bounds__(256) void styl_kernel(const uchar* __restrict__ y8,
                                                   const float* __restrict__ g,
                                                   const float* __restrict__ bb,
                                                   const float* __restrict__ embo,
                                                   uchar* __restrict__ a8) {
    int tid = threadIdx.x, w = tid >> 6, lane = tid & 63;
    int row = blockIdx.x * 4 + w;
    int b = row >> 10;
    const uchar* rp = y8 + (size_t)row * D_;
    uchar* op = a8 + (size_t)row * D_;
    float v[16];
    float s = 0.f, s2 = 0.f;
#pragma unroll
    for (int i = 0; i < 4; i++) {
        unsigned u = ((const unsigned*)rp)[i * 64 + lane];
#pragma unroll
        for (int j = 0; j < 4; j++) {
            float f = dec8((uchar)(u >> (8 * j)));
            v[i * 4 + j] = f; s += f; s2 += f * f;
        }
    }
#pragma unroll
    for (int off = 32; off; off >>= 1) {
        s  += __shfl_xor(s,  off, 64);
        s2 += __shfl_xor(s2, off, 64);
    }
    float mu = s * (1.f / 1024.f);
    float rstd = rsqrtf(s2 * (1.f / 1024.f) - mu * mu + 1e-5f);
#pragma unroll
    for (int i = 0; i < 4; i++) {
        int c4 = i * 64 + lane;
        float4 gv  = ((const float4*)g)[c4];
        float4 bv  = ((const float4*)bb)[c4];
        float4 scv = ((const float4*)(embo + b * 2048))[c4];
        float4 shv = ((const float4*)(embo + b * 2048 + 1024))[c4];
        float h0 = (v[i*4+0] - mu) * rstd * gv.x + bv.x;
        float h1 = (v[i*4+1] - mu) * rstd * gv.y + bv.y;
        float h2 = (v[i*4+2] - mu) * rstd * gv.z + bv.z;
        float h3 = (v[i*4+3] - mu) * rstd * gv.w + bv.w;
        h0 = h0 * (1.f + scv.x) + shv.x;
        h1 = h1 * (1.f + scv.y) + shv.y;
        h2 = h2 * (1.f + scv.z) + shv.z;
        h3 = h3 * (1.f + scv.w) + shv.w;
        h0 = h0 / (1.f + __expf(-h0));
        h1 = h1 / (1.f + __expf(-h1));
        h2 = h2 / (1.f + __expf(-h2));
        h3 = h3 / (1.f + __expf(-h3));
        ((int*)op)[c4] = pk4_fp8(h0, h1, h2, h3);
    }
}

extern "C" void kernel_launch(void* const* d_in, const int* in_sizes, int n_in,
                              void* d_out, int out_size, void* d_ws, size_t ws_size,
                              hipStream_t stream) {
    const float* x    = (const float*)d_in[0];
    const float* xf   = (const float*)d_in[1];
    const float* emb  = (const float*)d_in[2];
    const float* ln_g = (const float*)d_in[3];
    const float* ln_b = (const float*)d_in[4];
    const float* cln_g= (const float*)d_in[5];
    const float* cln_b= (const float*)d_in[6];
    const float* Wq   = (const float*)d_in[7];
    const float* bq   = (const float*)d_in[8];
    const float* Wk   = (const float*)d_in[9];
    const float* bk   = (const float*)d_in[10];
    const float* Wv   = (const float*)d_in[11];
    const float* bv   = (const float*)d_in[12];
    const float* sln_g= (const float*)d_in[13];
    const float* sln_b= (const float*)d_in[14];
    const float* Wemb = (const float*)d_in[15];
    const float* bemb = (const float*)d_in[16];
    const float* Wout = (const float*)d_in[17];
    const float* bout = (const float*)d_in[18];
    float* out = (float*)d_out;

    char* wsp = (char*)d_ws;
    const size_t MB = 1024 * 1024;
    uchar* xn8  = (uchar*)(wsp);                  // 8192x1024 fp8   8 MB
    uchar* xfn8 = (uchar*)(wsp + 8 * MB);         // 2048x768  fp8  1.5 MB
    uchar* wq8  = (uchar*)(wsp + 10 * MB);        // 1024x1024 fp8   1 MB
    uchar* wk8  = (uchar*)(wsp + 11 * MB);        //                .75 MB
    uchar* wv8  = (uchar*)(wsp + 12 * MB);        //                .75 MB
    uchar* wo8  = (uchar*)(wsp + 13 * MB);        //                 1 MB
    uchar* q8   = (uchar*)(wsp + 14 * MB);        // 8192x1024 fp8   8 MB
    uchar* k8   = (uchar*)(wsp + 22 * MB);        // 2048x1024 fp8   2 MB
    uchar* vT8  = (uchar*)(wsp + 24 * MB);        // pre-swizzled    2 MB
    uchar* y8   = (uchar*)(wsp + 26 * MB);        // 8192x1024 fp8   8 MB
    uchar* a8   = (uchar*)(wsp + 34 * MB);        // 8192x1024 fp8   8 MB
    float* embo = (float*)(wsp + 42 * MB);        // 8x2048    f32  64 KB
    float* part = (float*)(wsp + 43 * MB);        // 8x8x2048  f32  512 KB

    prep_kernel<<<3712, 256, 0, stream>>>(x, xf, ln_g, ln_b, cln_g, cln_b,
                                          Wq, Wk, Wv, Wout, emb, Wemb,
                                          xn8, xfn8, wq8, wk8, wv8, wo8, part);

    qkv_gemm<<<832, 256, 0, stream>>>(xn8, xfn8, wq8, wk8, wv8, bq, bk, bv,
                                      q8, k8, vT8, part, bemb, embo);

    attn_mfma<<<2048, 256, 0, stream>>>(q8, k8, vT8, y8);

    styl_kernel<<<2048, 256, 0, stream>>>(y8, sln_g, sln_b, embo, a8);

    out_gemm<<<512, 256, 0, stream>>>(a8, wo8, bout, x, out);
}

// Round 7
// 229.659 us; speedup vs baseline: 1.3400x; 1.0181x over previous
//
#include <hip/hip_runtime.h>
#include <hip/hip_bf16.h>

typedef __hip_bfloat16 bf16;
typedef unsigned short ushort;
typedef unsigned char uchar;
typedef long i64;   // 64-bit on amdgcn
typedef __attribute__((ext_vector_type(4))) float f32x4;

#define B_ 8
#define T_ 1024
#define D_ 1024
#define N_ 256
#define L_ 768
#define H_ 16
#define HD_ 64
#define TE_ 2048

__device__ __forceinline__ void gld16(const void* g, void* l) {
    __builtin_amdgcn_global_load_lds((const __attribute__((address_space(1))) void*)g,
                                     (__attribute__((address_space(3))) void*)l,
                                     16, 0, 0);
}

__device__ __forceinline__ float bitf(unsigned u) { return __uint_as_float(u); }

// pack 4 f32 -> 4 fp8 e4m3 bytes (OCP on gfx950)
__device__ __forceinline__ int pk4_fp8(float a, float b, float c, float d) {
    int p = __builtin_amdgcn_cvt_pk_fp8_f32(a, b, 0, false);
    p = __builtin_amdgcn_cvt_pk_fp8_f32(c, d, p, true);
    return p;
}
__device__ __forceinline__ uchar pk1_fp8(float a) {
    int p = __builtin_amdgcn_cvt_pk_fp8_f32(a, a, 0, false);
    return (uchar)(p & 0xff);
}
// manual e4m3fn decode (avoids unverified cvt builtin)
__device__ __forceinline__ float dec8(uchar b) {
    int e = (b >> 3) & 15, m = b & 7;
    float mag = e ? (float)(8 + m) * bitf((unsigned)(117 + e) << 23)   // (1+m/8)*2^(e-7)
                  : (float)m * bitf(118u << 23);                        // m * 2^-9
    return (b & 0x80) ? -mag : mag;
}

// wave-per-row LayerNorm -> fp8 (no barriers, coalesced 256B ld / 256B st)
template <int NV>
__device__ __forceinline__ void ln_row(const float* __restrict__ rp,
                                       const float* __restrict__ g,
                                       const float* __restrict__ bb,
                                       uchar* __restrict__ op, int lane) {
    float4 va[NV];
#pragma unroll
    for (int i = 0; i < NV; i++) va[i] = ((const float4*)rp)[i * 64 + lane];
    float s = 0.f, s2 = 0.f;
#pragma unroll
    for (int i = 0; i < NV; i++) {
        s  += va[i].x + va[i].y + va[i].z + va[i].w;
        s2 += va[i].x * va[i].x + va[i].y * va[i].y + va[i].z * va[i].z + va[i].w * va[i].w;
    }
#pragma unroll
    for (int off = 32; off; off >>= 1) {
        s  += __shfl_xor(s,  off, 64);
        s2 += __shfl_xor(s2, off, 64);
    }
    const float inv_n = 1.f / (float)(NV * 256);
    float mu = s * inv_n;
    float var = s2 * inv_n - mu * mu;
    float rstd = rsqrtf(var + 1e-5f);
#pragma unroll
    for (int i = 0; i < NV; i++) {
        float4 gv = ((const float4*)g)[i * 64 + lane];
        float4 bv = ((const float4*)bb)[i * 64 + lane];
        ((int*)op)[i * 64 + lane] = pk4_fp8((va[i].x - mu) * rstd * gv.x + bv.x,
                                            (va[i].y - mu) * rstd * gv.y + bv.y,
                                            (va[i].z - mu) * rstd * gv.z + bv.z,
                                            (va[i].w - mu) * rstd * gv.w + bv.w);
    }
}

// ===== prep: LN rows [0,2560) | tcvt [2560,3456) | emb1 [3456,3712) =======
__global__ __launch_bounds__(256) void prep_kernel(
        const float* __restrict__ x, const float* __restrict__ xf,
        const float* __restrict__ g1, const float* __restrict__ b1,
        const float* __restrict__ g2, const float* __restrict__ b2,
        const float* __restrict__ Wq, const float* __restrict__ Wk,
        const float* __restrict__ Wv, const float* __restrict__ Wo,
        const float* __restrict__ emb, const float* __restrict__ Wemb,
        uchar* __restrict__ xn8, uchar* __restrict__ xfn8,
        uchar* __restrict__ wq8, uchar* __restrict__ wk8,
        uchar* __restrict__ wv8, uchar* __restrict__ wo8,
        float* __restrict__ part) {
    __shared__ __align__(16) char smem[16384];
    int bid = blockIdx.x;
    int tid = threadIdx.x;
    if (bid < 2560) {
        int w = tid >> 6, lane = tid & 63;
        int row = bid * 4 + w;          // blocks 0..2047: x rows; 2048..2559: xf rows
        if (row < B_ * T_) {
            ln_row<4>(x + (size_t)row * D_, g1, b1, xn8 + (size_t)row * D_, lane);
        } else {
            int r = row - B_ * T_;
            ln_row<3>(xf + (size_t)r * L_, g2, b2, xfn8 + (size_t)r * L_, lane);
        }
    } else if (bid < 3456) {
        uchar (*t)[65] = (uchar(*)[65])smem;
        int id = bid - 2560;
        int xb = id & 15, y = id >> 4;
        const float* W; uchar* Wt; int K, ky;
        if (y < 16)      { W = Wq; Wt = wq8; K = 1024; ky = y; }
        else if (y < 28) { W = Wk; Wt = wk8; K = 768;  ky = y - 16; }
        else if (y < 40) { W = Wv; Wt = wv8; K = 768;  ky = y - 28; }
        else             { W = Wo; Wt = wo8; K = 1024; ky = y - 40; }
        int k0 = ky * 64, n0 = xb * 64;
#pragma unroll
        for (int i = 0; i < 16; i++) {
            int e = tid + i * 256;
            int r = e >> 6, c = e & 63;
            t[r][c] = pk1_fp8(W[(size_t)(k0 + r) * D_ + n0 + c]);
        }
        __syncthreads();
#pragma unroll
        for (int i = 0; i < 4; i++) {
            int e = tid + i * 256;
            int r = e >> 4, cg = (e & 15) * 4;
            unsigned u = (unsigned)t[cg][r] | ((unsigned)t[cg + 1][r] << 8)
                       | ((unsigned)t[cg + 2][r] << 16) | ((unsigned)t[cg + 3][r] << 24);
            *(unsigned*)&Wt[(size_t)(n0 + r) * K + k0 + cg] = u;
        }
    } else {
        float* se  = (float*)smem;
        float* red = (float*)(smem + 8192);
        int id = bid - 3456;
        int j0 = (id & 31) * 64;
        int ks = id >> 5;
        int tx = tid & 15, ty = tid >> 4;
        int w = tid >> 6, lane = tid & 63;
#pragma unroll
        for (int b = 0; b < 8; b++) {
            float xv = emb[b * TE_ + ks * 256 + tid];
            se[b * 256 + tid] = xv / (1.f + __expf(-xv));
        }
        __syncthreads();
        float acc[8][4] = {};
#pragma unroll 4
        for (int i = 0; i < 16; i++) {
            int e = ty + 16 * i;
            float4 wv = *(const float4*)&Wemb[(size_t)(ks * 256 + e) * 2048 + j0 + tx * 4];
#pragma unroll
            for (int b = 0; b < 8; b++) {
                float s = se[b * 256 + e];
                acc[b][0] += s * wv.x; acc[b][1] += s * wv.y;
                acc[b][2] += s * wv.z; acc[b][3] += s * wv.w;
            }
        }
#pragma unroll
        for (int b = 0; b < 8; b++)
#pragma unroll
            for (int m = 0; m < 4; m++) {
                float v = acc[b][m];
                v += __shfl_down(v, 32, 64);
                v += __shfl_down(v, 16, 64);
                if (lane < 16) red[(w * 8 + b) * 64 + lane * 4 + m] = v;
            }
        __syncthreads();
        for (int o = tid; o < 512; o += 256) {
            int b = o >> 6, jl = o & 63;
            float s = red[(0 * 8 + b) * 64 + jl] + red[(1 * 8 + b) * 64 + jl]
                    + red[(2 * 8 + b) * 64 + jl] + red[(3 * 8 + b) * 64 + jl];
            part[((size_t)ks * 8 + b) * 2048 + j0 + jl] = s;
        }
    }
}

// ===== fp8 MFMA GEMM body: 128x128 tile, BK=64, 2-PHASE double-buffer =====
// (unchanged from R6 — at this structure's plateau; not this round's variable)
template <int MODE>
__device__ __forceinline__ void gemm_body(const uchar* __restrict__ Ap,
                                          const uchar* __restrict__ Bp,
                                          const float* __restrict__ bias,
                                          const float* __restrict__ res,
                                          void* __restrict__ Cout,
                                          int m0, int n0, int Ncols, int K,
                                          uchar* SH) {
    int tid = threadIdx.x;
    int w = tid >> 6, lane = tid & 63;
    int quad = lane >> 4, l15 = lane & 15;
    int wm = (w >> 1) * 64, wn = (w & 1) * 64;
    int lr4 = lane >> 2;          // row-within-16 for staging
    int sp4 = lane & 3;           // slot 0..3
    uchar* A0 = SH;
    uchar* B0 = SH + 8192;
    uchar* A1 = SH + 16384;
    uchar* B1 = SH + 24576;
    f32x4 acc[4][4] = {};

    auto stage = [&](int kt, uchar* As, uchar* Bs) {
#pragma unroll
        for (int j = 0; j < 2; j++) {
            int r = w * 32 + j * 16 + lr4;
            int gc = sp4 ^ (r & 3);
            gld16(&Ap[(size_t)(m0 + r) * K + kt + gc * 16], &As[(w * 32 + j * 16) * 64]);
        }
#pragma unroll
        for (int j = 0; j < 2; j++) {
            int r = w * 32 + j * 16 + lr4;
            int gc = sp4 ^ (r & 3);
            gld16(&Bp[(size_t)(n0 + r) * K + kt + gc * 16], &Bs[(w * 32 + j * 16) * 64]);
        }
    };
    auto compute = [&](const uchar* As, const uchar* Bs) {
#pragma unroll
        for (int kh = 0; kh < 2; kh++) {
            int c4 = kh * 2 + (quad >> 1);
            int sub = (quad & 1) * 8;
            int pos = (c4 ^ (l15 & 3)) * 16 + sub;
            i64 af[4], bfr[4];
#pragma unroll
            for (int mt = 0; mt < 4; mt++)
                af[mt] = *(const i64*)&As[(wm + mt * 16 + l15) * 64 + pos];
#pragma unroll
            for (int nt = 0; nt < 4; nt++)
                bfr[nt] = *(const i64*)&Bs[(wn + nt * 16 + l15) * 64 + pos];
#pragma unroll
            for (int mt = 0; mt < 4; mt++)
#pragma unroll
                for (int nt = 0; nt < 4; nt++)
                    acc[mt][nt] = __builtin_amdgcn_mfma_f32_16x16x32_fp8_fp8(af[mt], bfr[nt], acc[mt][nt], 0, 0, 0);
        }
    };

    int nt2 = K >> 6;             // 16 (K=1024) or 12 (K=768) — always even
    stage(0, A0, B0);
    __syncthreads();
    for (int t = 0; t + 2 <= nt2; t += 2) {
        stage((t + 1) * 64, A1, B1);   // next tile in flight under compute
        compute(A0, B0);
        __syncthreads();               // drains vmcnt + syncs A0/B0 reads
        if (t + 2 < nt2) stage((t + 2) * 64, A0, B0);
        compute(A1, B1);
        __syncthreads();
    }

    if (MODE == 0) {
        // bounce fp8 tile through SH[0..16K) (dead), then 16B coalesced stores
#pragma unroll
        for (int mt = 0; mt < 4; mt++)
#pragma unroll
            for (int nt = 0; nt < 4; nt++)
#pragma unroll
                for (int reg = 0; reg < 4; reg++) {
                    int rl = wm + mt * 16 + quad * 4 + reg;
                    int cl = wn + nt * 16 + l15;
                    SH[rl * 128 + cl] = pk1_fp8(acc[mt][nt][reg] + bias[n0 + cl]);
                }
        __syncthreads();
#pragma unroll
        for (int i = 0; i < 4; i++) {
            int row = (tid >> 3) + i * 32;
            int ch = (tid & 7) * 16;
            *(int4*)&((uchar*)Cout)[(size_t)(m0 + row) * Ncols + n0 + ch] =
                *(const int4*)&SH[row * 128 + ch];
        }
    } else {
#pragma unroll
        for (int mt = 0; mt < 4; mt++) {
#pragma unroll
            for (int nt = 0; nt < 4; nt++) {
#pragma unroll
                for (int reg = 0; reg < 4; reg++) {
                    int row = m0 + wm + mt * 16 + quad * 4 + reg;
                    int col = n0 + wn + nt * 16 + l15;
                    float v = acc[mt][nt][reg] + bias[col];
                    if (MODE == 1) {
                        v += res[(size_t)row * Ncols + col];
                        ((float*)Cout)[(size_t)row * Ncols + col] = v;
                    } else {
                        int b = row >> 8, n = row & 255;
                        int h = col >> 6, d = col & 63;
                        size_t addr = ((size_t)(b * 16 + h)) * 16384 + (size_t)d * 256
                                    + (((n >> 4) ^ (d & 15)) * 16) + (n & 15);
                        ((uchar*)Cout)[addr] = pk1_fp8(v);
                    }
                }
            }
        }
    }
}

// ===== fused Q/K/V projection + emb2 tail =================================
__global__ __launch_bounds__(256, 4) void qkv_gemm(const uchar* __restrict__ xn8,
                                                   const uchar* __restrict__ xfn8,
                                                   const uchar* __restrict__ wq8,
                                                   const uchar* __restrict__ wk8,
                                                   const uchar* __restrict__ wv8,
                                                   const float* __restrict__ bq,
                                                   const float* __restrict__ bk,
                                                   const float* __restrict__ bv,
                                                   uchar* __restrict__ q8,
                                                   uchar* __restrict__ k8,
                                                   uchar* __restrict__ vT8,
                                                   const float* __restrict__ part,
                                                   const float* __restrict__ bemb,
                                                   float* __restrict__ embo) {
    __shared__ __align__(16) uchar SH[32768];   // A0|B0|A1|B1 (bounce uses first 16K)
    int bid = blockIdx.x;
    if (bid < 512) {
        gemm_body<0>(xn8, wq8, bq, nullptr, q8,
                     (bid & 63) * 128, (bid >> 6) * 128, D_, D_, SH);
    } else if (bid < 640) {
        int id = bid - 512;
        gemm_body<0>(xfn8, wk8, bk, nullptr, k8,
                     (id & 15) * 128, (id >> 4) * 128, D_, L_, SH);
    } else if (bid < 768) {
        int id = bid - 640;
        gemm_body<2>(xfn8, wv8, bv, nullptr, vT8,
                     (id & 15) * 128, (id >> 4) * 128, D_, L_, SH);
    } else {
        int o = (bid - 768) * 256 + threadIdx.x;
        int b = o >> 11, j = o & 2047;
        float s = bemb[j];
#pragma unroll
        for (int ks = 0; ks < 8; ks++) s += part[((size_t)ks * 8 + b) * 2048 + j];
        embo[o] = s;
    }
}

// ===== output projection + residual (f32 out) =============================
__global__ __launch_bounds__(256, 4) void out_gemm(const uchar* __restrict__ a8,
                                                   const uchar* __restrict__ wo8,
                                                   const float* __restrict__ bout,
                                                   const float* __restrict__ x,
                                                   float* __restrict__ out) {
    __shared__ __align__(16) uchar SH[32768];
    int bid = blockIdx.x;
    gemm_body<1>(a8, wo8, bout, x, out,
                 (bid & 63) * 128, (bid >> 6) * 128, D_, D_, SH);
}

// ===== full-fp8 MFMA attention, swapped-QK^T + in-register P (T12) ========
// mfma(K,Q) -> lane holds S^T[n][q=l15]; PV's P^T B-frag assembled in regs
// via cvt_pk + 4 shfl per K=32 step. No P LDS round-trip, 4 barriers, 24 KB.
__global__ __launch_bounds__(256) void attn_mfma(const uchar* __restrict__ q8,
                                                 const uchar* __restrict__ k8,
                                                 const uchar* __restrict__ vT8,
                                                 uchar* __restrict__ y8) {
    __shared__ __align__(16) uchar KV[16384];  // K image, then V image
    __shared__ __align__(16) uchar P[8192];    // padded Q, later O bounce
    int tid = threadIdx.x;
    int w = tid >> 6, lane = tid & 63;
    int quad = lane >> 4, l15 = lane & 15;
    int bid = blockIdx.x;
    int work = (bid & 7) * 256 + (bid >> 3);   // XCD-bijective: 2048 = 8 * 256
    int t0 = (work & 15) * 64;
    int bh = work >> 4;
    int b = bh >> 4, h = bh & 15;
    int lln = lane >> 3, sp = lane & 7;

    // K DMA: 4 gld16/wave; line dn holds rows 2dn,2dn+1; slot p <- chunk c8=p^(dn&7)
#pragma unroll
    for (int j = 0; j < 4; j++) {
        int dn = w * 32 + j * 8 + lln;
        int c8 = sp ^ (dn & 7);
        int n = dn * 2 + (c8 >> 2);
        gld16(&k8[(size_t)(b * N_ + n) * D_ + h * 64 + (c8 & 3) * 16],
              &KV[(w * 32 + j * 8) * 128]);
    }
    // Q DMA into P region: row r padded to 128B, slot p <- chunk (p^(r&7))&3
#pragma unroll
    for (int j = 0; j < 2; j++) {
        int r = w * 16 + j * 8 + lln;
        int c = (sp ^ (r & 7)) & 3;
        gld16(&q8[(size_t)(b * T_ + t0 + r) * D_ + h * 64 + c * 16],
              &P[(w * 16 + j * 8) * 128]);
    }
    __syncthreads();   // (1) DMA done

    // Q B-fragments (lane l15 = q-col), same byte pattern as before
    int qrow = w * 16 + l15;
    i64 aq0, aq1;
    {
        int c0 = (quad >> 1);
        int c1 = 2 + (quad >> 1);
        aq0 = *(const i64*)&P[qrow * 128 + ((c0 ^ (qrow & 7)) * 16) + (quad & 1) * 8];
        aq1 = *(const i64*)&P[qrow * 128 + ((c1 ^ (qrow & 7)) * 16) + (quad & 1) * 8];
    }

    // S^T = K Q^T (swapped operands): sf[nt][reg] = S[n = nt*16+quad*4+reg][q = l15]
    f32x4 sf[16];
#pragma unroll
    for (int nt = 0; nt < 16; nt++) {
        int n = nt * 16 + l15;
        int dn = n >> 1, hn = n & 1;
        int c80 = (hn * 4 + 0 + (quad >> 1)) ^ (dn & 7);
        int c81 = (hn * 4 + 2 + (quad >> 1)) ^ (dn & 7);
        i64 b0 = *(const i64*)&KV[dn * 128 + c80 * 16 + (quad & 1) * 8];
        i64 b1 = *(const i64*)&KV[dn * 128 + c81 * 16 + (quad & 1) * 8];
        f32x4 z = {};
        f32x4 t = __builtin_amdgcn_mfma_f32_16x16x32_fp8_fp8(b0, aq0, z, 0, 0, 0);
        sf[nt] = __builtin_amdgcn_mfma_f32_16x16x32_fp8_fp8(b1, aq1, t, 0, 0, 0);
    }
    __syncthreads();   // (2) K reads done -> KV reusable for V

    // V DMA (identity copy of pre-swizzled vT8) — latency hidden under softmax
    const uchar* vbase = vT8 + (size_t)(b * 16 + h) * 16384;
#pragma unroll
    for (int j = 0; j < 4; j++) {
        gld16(&vbase[(w * 4 + j) * 1024 + lane * 16], &KV[(w * 4 + j) * 1024]);
    }

    // softmax denom for q=l15: thread-local sum over its 64 n, then quad reduce
    const float scale = 0.125f;
    float sm = 0.f;
#pragma unroll
    for (int nt = 0; nt < 16; nt++)
#pragma unroll
        for (int reg = 0; reg < 4; reg++) {
            float e = __expf(sf[nt][reg] * scale);
            sf[nt][reg] = e;
            sm += e;
        }
    sm += __shfl_xor(sm, 16, 64);
    sm += __shfl_xor(sm, 32, 64);
    float inv = 1.f / sm;
    __syncthreads();   // (3) V DMA drained

    // O^T = V^T P^T: A = V^T frag from LDS, B = P^T frag assembled in regs
    f32x4 of[4] = {};
    int srcLo = 32 * (quad & 1) + l15;
#pragma unroll
    for (int kk = 0; kk < 8; kk++) {
        int pkA = pk4_fp8(sf[2 * kk][0], sf[2 * kk][1], sf[2 * kk][2], sf[2 * kk][3]);
        int pkB = pk4_fp8(sf[2 * kk + 1][0], sf[2 * kk + 1][1], sf[2 * kk + 1][2], sf[2 * kk + 1][3]);
        int loA = __shfl(pkA, srcLo, 64);
        int hiA = __shfl(pkA, srcLo + 16, 64);
        int loB = __shfl(pkB, srcLo, 64);
        int hiB = __shfl(pkB, srcLo + 16, 64);
        unsigned lo = (quad >> 1) ? (unsigned)loB : (unsigned)loA;
        unsigned hi = (quad >> 1) ? (unsigned)hiB : (unsigned)hiA;
        i64 pf = (i64)(((unsigned long long)hi << 32) | (unsigned long long)lo);
        int ck = kk * 2 + (quad >> 1);
#pragma unroll
        for (int dt = 0; dt < 4; dt++) {
            int d = dt * 16 + l15;
            i64 bv = *(const i64*)&KV[d * 256 + ((ck ^ (d & 15)) * 16) + (quad & 1) * 8];
            of[dt] = __builtin_amdgcn_mfma_f32_16x16x32_fp8_fp8(bv, pf, of[dt], 0, 0, 0);
        }
    }

    // bounce O^T -> P region as [q][d] rows (int writes, XOR-swizzled chunks)
    // of[dt][reg] = O[q = w*16+l15][d = dt*16 + quad*4 + reg]
#pragma unroll
    for (int dt = 0; dt < 4; dt++) {
        int ov = pk4_fp8(of[dt][0] * inv, of[dt][1] * inv, of[dt][2] * inv, of[dt][3] * inv);
        *(int*)&P[qrow * 64 + ((dt ^ (l15 & 3)) * 16) + quad * 4] = ov;
    }
    __syncthreads();   // (4) bounce visible
    {
        int row = tid >> 2, c = tid & 3;
        *(int4*)&y8[(size_t)(b * T_ + t0 + row) * D_ + h * 64 + c * 16] =
            *(const int4*)&P[row * 64 + ((c ^ (row & 3)) * 16)];
    }
}

// ===== stylization: wave-per-row, fp8 y in -> fp8 a out (no barriers) =====
__global__ __launch_bounds__(256) void styl_kernel(const uchar* __restrict__ y8,
                                                   const float* __restrict__ g,
                                                   const float* __restrict__ bb,
                                                   const float* __restrict__ embo,
                                                   uchar* __restrict__ a8) {
    int tid = threadIdx.x, w = tid >> 6, lane = tid & 63;
    int row = blockIdx.x * 4 + w;
    int b = row >> 10;
    const uchar* rp = y8 + (size_t)row * D_;
    uchar* op = a8 + (size_t)row * D_;
    float v[16];
    float s = 0.f, s2 = 0.f;
#pragma unroll
    for (int i = 0; i < 4; i++) {
        unsigned u = ((const unsigned*)rp)[i * 64 + lane];
#pragma unroll
        for (int j = 0; j < 4; j++) {
            float f = dec8((uchar)(u >> (8 * j)));
            v[i * 4 + j] = f; s += f; s2 += f * f;
        }
    }
#pragma unroll
    for (int off = 32; off; off >>= 1) {
        s  += __shfl_xor(s,  off, 64);
        s2 += __shfl_xor(s2, off, 64);
    }
    float mu = s * (1.f / 1024.f);
    float rstd = rsqrtf(s2 * (1.f / 1024.f) - mu * mu + 1e-5f);
#pragma unroll
    for (int i = 0; i < 4; i++) {
        int c4 = i * 64 + lane;
        float4 gv  = ((const float4*)g)[c4];
        float4 bv  = ((const float4*)bb)[c4];
        float4 scv = ((const float4*)(embo + b * 2048))[c4];
        float4 shv = ((const float4*)(embo + b * 2048 + 1024))[c4];
        float h0 = (v[i*4+0] - mu) * rstd * gv.x + bv.x;
        float h1 = (v[i*4+1] - mu) * rstd * gv.y + bv.y;
        float h2 = (v[i*4+2] - mu) * rstd * gv.z + bv.z;
        float h3 = (v[i*4+3] - mu) * rstd * gv.w + bv.w;
        h0 = h0 * (1.f + scv.x) + shv.x;
        h1 = h1 * (1.f + scv.y) + shv.y;
        h2 = h2 * (1.f + scv.z) + shv.z;
        h3 = h3 * (1.f + scv.w) + shv.w;
        h0 = h0 / (1.f + __expf(-h0));
        h1 = h1 / (1.f + __expf(-h1));
        h2 = h2 / (1.f + __expf(-h2));
        h3 = h3 / (1.f + __expf(-h3));
        ((int*)op)[c4] = pk4_fp8(h0, h1, h2, h3);
    }
}

extern "C" void kernel_launch(void* const* d_in, const int* in_sizes, int n_in,
                              void* d_out, int out_size, void* d_ws, size_t ws_size,
                              hipStream_t stream) {
    const float* x    = (const float*)d_in[0];
    const float* xf   = (const float*)d_in[1];
    const float* emb  = (const float*)d_in[2];
    const float* ln_g = (const float*)d_in[3];
    const float* ln_b = (const float*)d_in[4];
    const float* cln_g= (const float*)d_in[5];
    const float* cln_b= (const float*)d_in[6];
    const float* Wq   = (const float*)d_in[7];
    const float* bq   = (const float*)d_in[8];
    const float* Wk   = (const float*)d_in[9];
    const float* bk   = (const float*)d_in[10];
    const float* Wv   = (const float*)d_in[11];
    const float* bv   = (const float*)d_in[12];
    const float* sln_g= (const float*)d_in[13];
    const float* sln_b= (const float*)d_in[14];
    const float* Wemb = (const float*)d_in[15];
    const float* bemb = (const float*)d_in[16];
    const float* Wout = (const float*)d_in[17];
    const float* bout = (const float*)d_in[18];
    float* out = (float*)d_out;

    char* wsp = (char*)d_ws;
    const size_t MB = 1024 * 1024;
    uchar* xn8  = (uchar*)(wsp);                  // 8192x1024 fp8   8 MB
    uchar* xfn8 = (uchar*)(wsp + 8 * MB);         // 2048x768  fp8  1.5 MB
    uchar* wq8  = (uchar*)(wsp + 10 * MB);        // 1024x1024 fp8   1 MB
    uchar* wk8  = (uchar*)(wsp + 11 * MB);        //                .75 MB
    uchar* wv8  = (uchar*)(wsp + 12 * MB);        //                .75 MB
    uchar* wo8  = (uchar*)(wsp + 13 * MB);        //                 1 MB
    uchar* q8   = (uchar*)(wsp + 14 * MB);        // 8192x1024 fp8   8 MB
    uchar* k8   = (uchar*)(wsp + 22 * MB);        // 2048x1024 fp8   2 MB
    uchar* vT8  = (uchar*)(wsp + 24 * MB);        // pre-swizzled    2 MB
    uchar* y8   = (uchar*)(wsp + 26 * MB);        // 8192x1024 fp8   8 MB
    uchar* a8   = (uchar*)(wsp + 34 * MB);        // 8192x1024 fp8   8 MB
    float* embo = (float*)(wsp + 42 * MB);        // 8x2048    f32  64 KB
    float* part = (float*)(wsp + 43 * MB);        // 8x8x2048  f32  512 KB

    prep_kernel<<<3712, 256, 0, stream>>>(x, xf, ln_g, ln_b, cln_g, cln_b,
                                          Wq, Wk, Wv, Wout, emb, Wemb,
                                          xn8, xfn8, wq8, wk8, wv8, wo8, part);

    qkv_gemm<<<832, 256, 0, stream>>>(xn8, xfn8, wq8, wk8, wv8, bq, bk, bv,
                                      q8, k8, vT8, part, bemb, embo);

    attn_mfma<<<2048, 256, 0, stream>>>(q8, k8, vT8, y8);

    styl_kernel<<<2048, 256, 0, stream>>>(y8, sln_g, sln_b, embo, a8);

    out_gemm<<<512, 256, 0, stream>>>(a8, wo8, bout, x, out);
}